// Round 15
// baseline (445.257 us; speedup 1.0000x reference)
//
#include <hip/hip_runtime.h>
#include <hip/hip_bf16.h>
#include <math.h>

#define Bb 16
#define Tt 32
#define Vv 26
#define Nn 500
#define Uu 64
#define Hh 512
#define CIN 209
#define K1P 256
#define Mm 512
#define Rr 256000
#define NB1 4000
#define NB23 2000

typedef short short8 __attribute__((ext_vector_type(8)));
typedef float f32x4 __attribute__((ext_vector_type(4)));

__device__ __forceinline__ float sigf(float x){ return 1.0f/(1.0f+expf(-x)); }
__device__ __forceinline__ float frcp(float x){ return __builtin_amdgcn_rcpf(x); }
__device__ __forceinline__ unsigned short f2bf(float f){
  __hip_bfloat16 h = __float2bfloat16(f);
  return *reinterpret_cast<unsigned short*>(&h);
}
__device__ __forceinline__ float bf2f(unsigned short h){
  return __uint_as_float(((unsigned)h)<<16);
}

// ---------------- front fusion: wprep converts + W1B pad | embw dots | bn0 partial stats ----------------
__global__ void k_front(const float* __restrict__ W2, const float* __restrict__ W3,
                        const float* __restrict__ EMB, const float* __restrict__ WIH,
                        const float* __restrict__ BIH, const float* __restrict__ BHH,
                        const float* __restrict__ L, const float* __restrict__ PL,
                        const float* __restrict__ PI, const float* __restrict__ DSF,
                        unsigned short* __restrict__ W2B, unsigned short* __restrict__ W3B,
                        unsigned short* __restrict__ W1B,
                        float* __restrict__ embw, float* __restrict__ ps0){
  int bid = blockIdx.x;
  int tid = threadIdx.x;
  if (bid < 172){
    int idx = bid*256 + tid;
    if (idx < 8192){ W2B[idx] = f2bf(W2[idx]); return; }
    idx -= 8192;
    if (idx < 32768){ W3B[idx] = f2bf(W3[idx]); return; }
    idx -= 32768;
    if (idx < 3008){ int oo = idx/47, kk = 209 + idx - (idx/47)*47; W1B[oo*K1P + kk] = 0; }
    return;
  }
  if (bid < 13484){
    int gw = (bid-172)*4 + (tid>>6);
    int lane = tid & 63;
    int v = gw >> 11;
    int j = gw & 2047;
    const float4* ea = (const float4*)&EMB[(size_t)v*512];
    const float4* wa = (const float4*)&WIH[(size_t)j*512];
    float4 e0 = ea[lane*2], e1 = ea[lane*2+1];
    float4 w0 = wa[lane*2], w1 = wa[lane*2+1];
    float s = e0.x*w0.x + e0.y*w0.y + e0.z*w0.z + e0.w*w0.w
            + e1.x*w1.x + e1.y*w1.y + e1.z*w1.z + e1.w*w1.w;
    #pragma unroll
    for (int off=1; off<64; off<<=1) s += __shfl_xor(s,off);
    if (lane==0) embw[(size_t)v*2048 + j] = s + BIH[j] + BHH[j];
    return;
  }
  int fid = bid - 13484;
  int m = fid>>3, q = fid&7;
  int b = m >> 5;
  int n0 = q*62 + ((q<4)?q:4);
  int cnt = 62 + (q<4 ? 1 : 0);
  __shared__ float pl_sh[63], pi_sh[63];
  for (int n=tid; n<cnt; n+=256){ pl_sh[n]=PL[b*Nn+n0+n]; pi_sh[n]=PI[b*Nn+n0+n]; }
  __syncthreads();
  if (tid >= CIN) return;
  float sum=0.f, sq=0.f;
  if (tid < CIN-1){
    float li = L[m*208 + tid];
    if (li > 1e-5f){
      float cfac = sigf(DSF[0])*200000.0f;
      float si = frcp(li + 1e-6f)*cfac;
      for (int n=0;n<cnt;n++){
        float pl = pl_sh[n];
        float f = (pl > 1e-5f) ? __expf(-fabsf((pl-li)*si)) : 0.f;
        sum += f; sq += f*f;
      }
    }
  } else {
    for (int n=0;n<cnt;n++){ float v=pi_sh[n]; sum+=v; sq+=v*v; }
  }
  int pb = m*8+q;
  ps0[(size_t)pb*CIN + tid] = sum;
  ps0[(size_t)(4096+pb)*CIN + tid] = sq;
}

// bn0 reduce + fold into W1B column (bb0 cancels through bn1; only scale needed)
__global__ void k_reduce0(const float* __restrict__ ps, const float* __restrict__ g,
                          const float* __restrict__ w1, unsigned short* __restrict__ w1b){
  int c = blockIdx.x;
  int tid = threadIdx.x;
  float s=0.f, q=0.f;
  for (int nb=tid; nb<4096; nb+=256){
    s += ps[(size_t)nb*CIN + c];
    q += ps[(size_t)(4096+nb)*CIN + c];
  }
  #pragma unroll
  for (int off=1; off<64; off<<=1){ s += __shfl_xor(s,off); q += __shfl_xor(q,off); }
  __shared__ float rs[4], rq[4];
  __shared__ float a_sh;
  if ((tid&63)==0){ rs[tid>>6]=s; rq[tid>>6]=q; }
  __syncthreads();
  if (tid==0){
    s = rs[0]+rs[1]+rs[2]+rs[3]; q = rq[0]+rq[1]+rq[2]+rq[3];
    float mean = s/(float)Rr;
    float var  = q/(float)Rr - mean*mean;
    a_sh = g[c]*rsqrtf(var + 1e-5f);
  }
  __syncthreads();
  if (tid < 64) w1b[tid*K1P + c] = f2bf(w1[tid*CIN + c] * a_sh);
}

// per-channel reduce of per-block partials -> (a, bb)
__global__ void k_reduce_ps(const float* __restrict__ ps, int NB, int C, float invCount,
                            const float* __restrict__ g, const float* __restrict__ bt,
                            float* __restrict__ abb){
  int c = blockIdx.x;
  int tid = threadIdx.x;
  float s=0.f, q=0.f;
  for (int nb=tid; nb<NB; nb+=256){
    s += ps[(size_t)nb*C + c];
    q += ps[(size_t)(NB+nb)*C + c];
  }
  #pragma unroll
  for (int off=1; off<64; off<<=1){ s += __shfl_xor(s,off); q += __shfl_xor(q,off); }
  __shared__ float rs[4], rq[4];
  if ((tid&63)==0){ rs[tid>>6]=s; rq[tid>>6]=q; }
  __syncthreads();
  if (tid==0){
    s = rs[0]+rs[1]+rs[2]+rs[3]; q = rq[0]+rq[1]+rq[2]+rq[3];
    float mean = s*invCount;
    float var  = q*invCount - mean*mean;
    float istd = rsqrtf(var + 1e-5f);
    float a = g[c]*istd;
    abb[c] = a;
    abb[C+c] = bt[c] - mean*a;
  }
}

// parallel per-column mean/var over Mrows -> (a, bb); one block per column
__global__ void k_colstats_par(const float* __restrict__ Z, int Mrows, int C,
                               const float* __restrict__ g, const float* __restrict__ bt,
                               float* __restrict__ abb){
  int c = blockIdx.x;
  int tid = threadIdx.x;
  float s=0.f,q=0.f;
  for (int r=tid; r<Mrows; r+=256){ float v=Z[(size_t)r*C+c]; s+=v; q+=v*v; }
  #pragma unroll
  for (int off=1; off<64; off<<=1){ s += __shfl_xor(s,off); q += __shfl_xor(q,off); }
  __shared__ float rs[4], rq[4];
  if ((tid&63)==0){ rs[tid>>6]=s; rq[tid>>6]=q; }
  __syncthreads();
  if (tid==0){
    s = rs[0]+rs[1]+rs[2]+rs[3]; q = rq[0]+rq[1]+rq[2]+rq[3];
    float mean = s/(float)Mrows;
    float var  = q/(float)Mrows - mean*mean;
    float istd = rsqrtf(var + 1e-5f);
    float a = g[c]*istd;
    abb[c]=a; abb[C+c]=bt[c]-mean*a;
  }
}

// ---------------- conv1 MFMA: K-chunked (2x128); A and B staged in LDS ----------------
__launch_bounds__(256)
__global__ void k_conv1mf(const float* __restrict__ L, const float* __restrict__ PL,
                          const float* __restrict__ PI, const float* __restrict__ DSF,
                          const unsigned short* __restrict__ W1B,
                          unsigned short* __restrict__ Z1B, float* __restrict__ ps){
  __shared__ __align__(16) unsigned short Abuf[64*128];
  __shared__ __align__(16) unsigned short Bbuf[64*128];
  __shared__ __align__(16) float si_s[2][208];
  __shared__ float pl_s[64], pi_s[64];
  __shared__ int mi_i[64];
  __shared__ float red[4][2][64];
  int tid = threadIdx.x;
  int r0 = blockIdx.x*64;
  int m0 = r0/500, m1 = (r0+63)/500;
  float cfac = sigf(DSF[0])*200000.0f;
  if (tid < 64){
    int r = r0+tid; int m = r/500; int n = r - m*500; int b = m >> 5;
    pl_s[tid] = PL[b*Nn+n]; pi_s[tid] = PI[b*Nn+n]; mi_i[tid] = (m == m0) ? 0 : 1;
  }
  for (int j=tid; j<416; j+=256){
    int gg = (j>=208) ? 1 : 0; int jj = j - gg*208;
    float li = L[(size_t)(gg?m1:m0)*208 + jj];
    si_s[gg][jj] = (li > 1e-5f) ? frcp(li+1e-6f)*cfac : -1.0f;
  }
  int lane = tid&63, wid = tid>>6;
  int l15 = lane&15, lhi = lane>>4;
  int ar = wid*16 + l15;
  unsigned aswz = ((unsigned)(ar&7))<<4;
  f32x4 acc[4] = {};
  __syncthreads();
  for (int kc=0; kc<2; kc++){
    if (kc) __syncthreads();
    for (int e=tid; e<1024; e+=256){
      int row = e>>4; int k4 = (e&15)*8;
      short8 w = *(const short8*)&W1B[row*K1P + kc*128 + k4];
      unsigned byte = ((unsigned)(row*128 + k4))*2u ^ (((unsigned)(row&7))<<4);
      *(short8*)((char*)Bbuf + byte) = w;
    }
    for (int e=tid; e<1024; e+=256){
      int row = e>>4; int j0l = (e&15)*8;
      int jg = kc*128 + j0l;
      float pl = pl_s[row];
      bool plok = pl > 1e-5f;
      short8 st;
      if (jg < 208){
        int mi = mi_i[row];
        const float* lp = &L[(size_t)(mi?m1:m0)*208 + jg];
        float4 la = *(const float4*)lp;
        float4 lb = *(const float4*)(lp+4);
        float4 sa = *(const float4*)&si_s[mi][jg];
        float4 sb = *(const float4*)&si_s[mi][jg+4];
        float li[8] = {la.x,la.y,la.z,la.w,lb.x,lb.y,lb.z,lb.w};
        float si[8] = {sa.x,sa.y,sa.z,sa.w,sb.x,sb.y,sb.z,sb.w};
        #pragma unroll
        for (int j=0;j<8;j++){
          float v = (plok && si[j] >= 0.f) ? __expf(-fabsf((pl-li[j])*si[j])) : 0.f;
          st[j] = (short)f2bf(v);
        }
      } else {
        #pragma unroll
        for (int j=0;j<8;j++) st[j] = 0;
        if (jg == 208) st[0] = (short)f2bf(pi_s[row]);
      }
      unsigned byte = ((unsigned)(row*128 + j0l))*2u ^ (((unsigned)(row&7))<<4);
      *(short8*)((char*)Abuf + byte) = st;
    }
    __syncthreads();
    #pragma unroll
    for (int ks=0; ks<4; ks++){
      int kb = ks*32 + lhi*8;
      short8 af = *(const short8*)((const char*)Abuf + ((((unsigned)(ar*128 + kb))*2u) ^ aswz));
      #pragma unroll
      for (int fj=0; fj<4; fj++){
        int bc = fj*16 + l15;
        short8 bfv = *(const short8*)((const char*)Bbuf + ((((unsigned)(bc*128 + kb))*2u) ^ (((unsigned)(bc&7))<<4)));
        acc[fj] = __builtin_amdgcn_mfma_f32_16x16x32_bf16(af, bfv, acc[fj], 0, 0, 0);
      }
    }
  }
  #pragma unroll
  for (int fj=0; fj<4; fj++){
    int ch = fj*16 + l15;
    float s=0.f, q=0.f;
    #pragma unroll
    for (int qi=0; qi<4; qi++){
      float zv = acc[fj][qi];
      int rg = r0 + wid*16 + lhi*4 + qi;
      Z1B[(size_t)rg*Uu + ch] = f2bf(zv);
      s += zv; q = fmaf(zv,zv,q);
    }
    s += __shfl_xor(s,16); s += __shfl_xor(s,32);
    q += __shfl_xor(q,16); q += __shfl_xor(q,32);
    if (lhi == 0){ red[wid][0][ch]=s; red[wid][1][ch]=q; }
  }
  __syncthreads();
  if (tid < 64){
    float s = red[0][0][tid]+red[1][0][tid]+red[2][0][tid]+red[3][0][tid];
    float q = red[0][1][tid]+red[1][1][tid]+red[2][1][tid]+red[3][1][tid];
    ps[(size_t)blockIdx.x*Uu + tid] = s;
    ps[(size_t)(NB1 + blockIdx.x)*Uu + tid] = q;
  }
}

// ---------------- conv2 MFMA: A in LDS, B preloaded to VGPRs ----------------
__launch_bounds__(256,4)
__global__ void k_convmf(const unsigned short* __restrict__ Xin, const float* __restrict__ abbIn,
                         const unsigned short* __restrict__ Wb,
                         unsigned short* __restrict__ Zout,
                         float* __restrict__ ps, int NB){
  constexpr int K = 64, Ctot = 128;
  __shared__ __align__(16) unsigned short Abuf[128*K];
  __shared__ float abbs[2*K];
  __shared__ float redS[2][128], redQ[2][128];
  int tid = threadIdx.x;
  int r0 = blockIdx.x*128;
  int lane = tid&63, wid = tid>>6;
  int wr = wid>>1, wc = wid&1;
  int l15 = lane&15, lhi = lane>>4;
  // preload all B fragments (issued before staging; latency hides under it)
  short8 bfv[8];
  #pragma unroll
  for (int ks=0; ks<2; ks++)
    #pragma unroll
    for (int f=0; f<4; f++){
      int kb = ks*32 + lhi*8;
      int bc = wc*64 + f*16 + l15;
      bfv[ks*4+f] = *(const short8*)&Wb[(size_t)bc*K + kb];
    }
  for (int e=tid; e<2*K; e+=256) abbs[e] = abbIn[e];
  __syncthreads();
  constexpr int CPR = K/8;
  for (int e=tid; e<128*CPR; e+=256){
    int row = e/CPR; int kc = (e - row*CPR)*8;
    short8 rawv = *(const short8*)(Xin + (size_t)(r0+row)*K + kc);
    short8 st;
    #pragma unroll
    for (int j=0;j<8;j++){
      float t = fmaxf(abbs[kc+j]*bf2f((unsigned short)rawv[j]) + abbs[K+kc+j], 0.f);
      st[j] = (short)f2bf(t);
    }
    unsigned byte = ((unsigned)(row*K + kc))*2u; byte ^= ((unsigned)(row&7))<<4;
    *(short8*)((char*)Abuf + byte) = st;
  }
  __syncthreads();

  f32x4 acc[4][4] = {};
  #pragma unroll
  for (int ks=0; ks<K/32; ks++){
    short8 af[4];
    int kb = ks*32 + lhi*8;
    #pragma unroll
    for (int f=0; f<4; f++){
      int arr = wr*64 + f*16 + l15;
      unsigned ab = ((unsigned)(arr*K + kb))*2u ^ (((unsigned)(arr&7))<<4);
      af[f] = *(const short8*)((const char*)Abuf + ab);
    }
    #pragma unroll
    for (int fi=0; fi<4; fi++)
      #pragma unroll
      for (int fj=0; fj<4; fj++)
        acc[fi][fj] = __builtin_amdgcn_mfma_f32_16x16x32_bf16(af[fi], bfv[ks*4+fj], acc[fi][fj], 0, 0, 0);
  }

  #pragma unroll
  for (int fj=0; fj<4; fj++){
    int cg = wc*64 + fj*16 + l15;
    float s=0.f, q=0.f;
    #pragma unroll
    for (int fi=0; fi<4; fi++){
      #pragma unroll
      for (int qi=0; qi<4; qi++){
        float zv = acc[fi][fj][qi];
        int rg = r0 + wr*64 + fi*16 + lhi*4 + qi;
        Zout[(size_t)rg*Ctot + cg] = f2bf(zv);
        s += zv; q = fmaf(zv,zv,q);
      }
    }
    s += __shfl_xor(s,16); s += __shfl_xor(s,32);
    q += __shfl_xor(q,16); q += __shfl_xor(q,32);
    if (lhi == 0){ redS[wr][cg]=s; redQ[wr][cg]=q; }
  }
  __syncthreads();
  if (tid < 128){
    float s = redS[0][tid]+redS[1][tid];
    float q = redQ[0][tid]+redQ[1][tid];
    size_t ci = (size_t)blockIdx.x*Ctot + tid;
    ps[ci] = s;
    ps[(size_t)NB*Ctot + ci] = q;
  }
}

// ---------------- conv3 MFMA: A in LDS once, B preloaded to VGPRs per half ----------------
__launch_bounds__(256,3)
__global__ void k_conv3mf(const unsigned short* __restrict__ Xin, const float* __restrict__ abbIn,
                          const unsigned short* __restrict__ Wb,
                          float* __restrict__ ps, int NB,
                          float* __restrict__ pm, float* __restrict__ pn){
  constexpr int K = 128, Ctot = 256;
  __shared__ __align__(16) unsigned short Abuf[128*K];
  __shared__ float abbs[2*K];
  __shared__ float redS[2][128], redQ[2][128];
  __shared__ float mxS[2][2][128], mnS[2][2][128];
  int tid = threadIdx.x;
  int r0 = blockIdx.x*128;
  int lane = tid&63, wid = tid>>6;
  int wr = wid>>1, wc = wid&1;
  int l15 = lane&15, lhi = lane>>4;
  // preload half-0 B fragments (latency hides under A staging)
  short8 bfv[16];
  #pragma unroll
  for (int ks=0; ks<4; ks++)
    #pragma unroll
    for (int f=0; f<4; f++){
      int kb = ks*32 + lhi*8;
      int bc = wc*64 + f*16 + l15;
      bfv[ks*4+f] = *(const short8*)&Wb[(size_t)bc*K + kb];
    }
  for (int e=tid; e<2*K; e+=256) abbs[e] = abbIn[e];
  __syncthreads();
  constexpr int CPR = K/8;
  for (int e=tid; e<128*CPR; e+=256){
    int row = e/CPR; int kc = (e - row*CPR)*8;
    short8 rawv = *(const short8*)(Xin + (size_t)(r0+row)*K + kc);
    short8 st;
    #pragma unroll
    for (int j=0;j<8;j++){
      float t = fmaxf(abbs[kc+j]*bf2f((unsigned short)rawv[j]) + abbs[K+kc+j], 0.f);
      st[j] = (short)f2bf(t);
    }
    unsigned byte = ((unsigned)(row*K + kc))*2u; byte ^= ((unsigned)(row&7))<<4;
    *(short8*)((char*)Abuf + byte) = st;
  }
  __syncthreads();

  int m0 = r0/500;
  int mhi = (m0+1)*500;
  bool onem = (r0+127) < mhi;

  for (int half=0; half<2; half++){
    int c0 = half*128;
    if (half){
      // preload half-1 B (overlaps with prior epilogue drain)
      #pragma unroll
      for (int ks=0; ks<4; ks++)
        #pragma unroll
        for (int f=0; f<4; f++){
          int kb = ks*32 + lhi*8;
          int bc = c0 + wc*64 + f*16 + l15;
          bfv[ks*4+f] = *(const short8*)&Wb[(size_t)bc*K + kb];
        }
      __syncthreads();   // redS/mxS reuse
    }

    f32x4 acc[4][4] = {};
    #pragma unroll
    for (int ks=0; ks<K/32; ks++){
      short8 af[4];
      int kb = ks*32 + lhi*8;
      #pragma unroll
      for (int f=0; f<4; f++){
        int arr = wr*64 + f*16 + l15;
        unsigned ab = ((unsigned)(arr*K + kb))*2u ^ (((unsigned)(arr&7))<<4);
        af[f] = *(const short8*)((const char*)Abuf + ab);
      }
      #pragma unroll
      for (int fi=0; fi<4; fi++)
        #pragma unroll
        for (int fj=0; fj<4; fj++)
          acc[fi][fj] = __builtin_amdgcn_mfma_f32_16x16x32_bf16(af[fi], bfv[ks*4+fj], acc[fi][fj], 0, 0, 0);
    }

    if (onem){
      #pragma unroll
      for (int fj=0; fj<4; fj++){
        float s=0.f, q=0.f, mx0=-INFINITY, mn0=INFINITY;
        #pragma unroll
        for (int fi=0; fi<4; fi++){
          #pragma unroll
          for (int qi=0; qi<4; qi++){
            float zv = acc[fi][fj][qi];
            s += zv; q = fmaf(zv,zv,q);
            mx0 = fmaxf(mx0,zv); mn0 = fminf(mn0,zv);
          }
        }
        s += __shfl_xor(s,16); s += __shfl_xor(s,32);
        q += __shfl_xor(q,16); q += __shfl_xor(q,32);
        mx0 = fmaxf(mx0, __shfl_xor(mx0,16)); mx0 = fmaxf(mx0, __shfl_xor(mx0,32));
        mn0 = fminf(mn0, __shfl_xor(mn0,16)); mn0 = fminf(mn0, __shfl_xor(mn0,32));
        if (lhi == 0){
          int ch = wc*64 + fj*16 + l15;
          redS[wr][ch]=s; redQ[wr][ch]=q;
          mxS[wr][0][ch]=mx0; mxS[wr][1][ch]=-INFINITY;
          mnS[wr][0][ch]=mn0; mnS[wr][1][ch]=INFINITY;
        }
      }
    } else {
      #pragma unroll
      for (int fj=0; fj<4; fj++){
        float s=0.f, q=0.f;
        float mx0=-INFINITY,mx1=-INFINITY,mn0=INFINITY,mn1=INFINITY;
        #pragma unroll
        for (int fi=0; fi<4; fi++){
          #pragma unroll
          for (int qi=0; qi<4; qi++){
            float zv = acc[fi][fj][qi];
            int rg = r0 + wr*64 + fi*16 + lhi*4 + qi;
            s += zv; q = fmaf(zv,zv,q);
            if (rg >= mhi){ mx1=fmaxf(mx1,zv); mn1=fminf(mn1,zv); }
            else          { mx0=fmaxf(mx0,zv); mn0=fminf(mn0,zv); }
          }
        }
        s += __shfl_xor(s,16); s += __shfl_xor(s,32);
        q += __shfl_xor(q,16); q += __shfl_xor(q,32);
        mx0 = fmaxf(mx0, __shfl_xor(mx0,16)); mx0 = fmaxf(mx0, __shfl_xor(mx0,32));
        mx1 = fmaxf(mx1, __shfl_xor(mx1,16)); mx1 = fmaxf(mx1, __shfl_xor(mx1,32));
        mn0 = fminf(mn0, __shfl_xor(mn0,16)); mn0 = fminf(mn0, __shfl_xor(mn0,32));
        mn1 = fminf(mn1, __shfl_xor(mn1,16)); mn1 = fminf(mn1, __shfl_xor(mn1,32));
        if (lhi == 0){
          int ch = wc*64 + fj*16 + l15;
          redS[wr][ch]=s; redQ[wr][ch]=q;
          mxS[wr][0][ch]=mx0; mxS[wr][1][ch]=mx1;
          mnS[wr][0][ch]=mn0; mnS[wr][1][ch]=mn1;
        }
      }
    }
    __syncthreads();
    if (tid < 128){
      float s = redS[0][tid]+redS[1][tid];
      float q = redQ[0][tid]+redQ[1][tid];
      size_t ci = (size_t)blockIdx.x*Ctot + c0 + tid;
      ps[ci] = s;
      ps[(size_t)NB*Ctot + ci] = q;
      #pragma unroll
      for (int g=0; g<2; g++){
        pm[((size_t)blockIdx.x*2+g)*Ctot + c0 + tid] = fmaxf(mxS[0][g][tid], mxS[1][g][tid]);
        pn[((size_t)blockIdx.x*2+g)*Ctot + c0 + tid] = fminf(mnS[0][g][tid], mnS[1][g][tid]);
      }
    }
  }
}

// ---------------- fused pool + FC1: one block per output row ----------------
__launch_bounds__(256)
__global__ void k_poolfc1(const float* __restrict__ pm, const float* __restrict__ pn,
                          const float* __restrict__ abb3, const float* __restrict__ FC1W,
                          float* __restrict__ Z4){
  __shared__ float of[256];
  int r = blockIdx.x;
  int tid = threadIdx.x;
  {
    int c = tid;
    int bxlo = (500*r)/128;
    int bxhi = (500*r+499)/128;
    float mx=-INFINITY, mn=INFINITY;
    for (int bx=bxlo; bx<=bxhi; bx++){
      int mb = (bx*128)/500;
      int gg = r - mb;
      if (gg==0 || gg==1){
        mx = fmaxf(mx, pm[((size_t)bx*2+gg)*256 + c]);
        mn = fminf(mn, pn[((size_t)bx*2+gg)*256 + c]);
      }
    }
    float a = abb3[c], bb = abb3[256+c];
    float zv = (a >= 0.f) ? mx : mn;
    of[c] = fmaxf(a*zv + bb, 0.f);
  }
  __syncthreads();
  if (tid < 128){
    float acc = 0.f;
    const float* wr = &FC1W[(size_t)tid*256];
    #pragma unroll 4
    for (int k=0;k<256;k++) acc = fmaf(of[k], wr[k], acc);
    Z4[(size_t)r*128 + tid] = acc;
  }
}

// ---------------- FC2: wave per output ----------------
__launch_bounds__(256)
__global__ void k_fc(const float* __restrict__ A, const float* __restrict__ W,
                     const float* __restrict__ abb, float* __restrict__ C,
                     int Ncols, int K){
  int gw = blockIdx.x*4 + (threadIdx.x>>6);
  int lane = threadIdx.x & 63;
  int r = gw / Ncols, c = gw - r*Ncols;
  float s = 0.f;
  for (int k=lane; k<K; k+=64){
    float v = A[(size_t)r*K + k];
    if (abb) v = fmaxf(abb[k]*v + abb[K+k], 0.f);
    s = fmaf(v, W[(size_t)c*K + k], s);
  }
  #pragma unroll
  for (int off=1; off<64; off<<=1) s += __shfl_xor(s,off);
  if (lane==0) C[(size_t)r*Ncols + c] = s;
}

// one LSTM step; 512 blocks (one u-column each) x 256 thr; wave = gate, lane = (seg,b)
__launch_bounds__(256)
__global__ void k_lstm_step(const float* __restrict__ hprev, float* __restrict__ hnext,
                            const float* __restrict__ cin, float* __restrict__ cout,
                            const float* __restrict__ embw, const int* __restrict__ aa,
                            const float* __restrict__ whh, float* __restrict__ lout,
                            float* __restrict__ outhc, int t){
  __shared__ float h_s[16][516];
  __shared__ float g_s[4][16];
  int tid = threadIdx.x;
  int u = blockIdx.x;
  for (int e=tid; e<2048; e+=256){
    int idx = e*4;
    *(float4*)&h_s[idx>>9][idx&511] = *(const float4*)&hprev[idx];
  }
  __syncthreads();
  int w = tid>>6, lane = tid&63;
  int seg = lane>>4, b = lane&15;
  int j = w*512 + u;
  const float4* wrow = (const float4*)&whh[(size_t)j*512] + seg*32;
  const float4* hrow = (const float4*)&h_s[b][0] + seg*32;
  float a0=0.f, a1=0.f, a2=0.f, a3=0.f;
  #pragma unroll 4
  for (int k=0;k<32;k++){
    float4 wv = wrow[k]; float4 hv = hrow[k];
    a0 = fmaf(hv.x,wv.x,a0); a1 = fmaf(hv.y,wv.y,a1);
    a2 = fmaf(hv.z,wv.z,a2); a3 = fmaf(hv.w,wv.w,a3);
  }
  float s = (a0+a1)+(a2+a3);
  s += __shfl_xor(s,16);
  s += __shfl_xor(s,32);
  if (lane < 16){
    int v = aa[lane*Tt + t];
    g_s[w][lane] = s + embw[(size_t)v*2048 + j];
  }
  __syncthreads();
  if (tid < 16){
    int b2 = tid;
    float iv = g_s[0][b2], fv = g_s[1][b2], gv = g_s[2][b2], ov = g_s[3][b2];
    int ci = b2*512 + u;
    float cn = sigf(fv)*cin[ci] + sigf(iv)*tanhf(gv);
    float hn = sigf(ov)*tanhf(cn);
    cout[ci]=cn; hnext[ci]=hn;
    lout[(size_t)(b2*Tt + t)*Hh + u] = hn;
    if (outhc){ outhc[Mm*Vv + ci] = hn; outhc[Mm*Vv + Bb*Hh + ci] = cn; }
  }
}

// logits: one block per output row; 8-lane dot groups over 26 outputs
__launch_bounds__(256)
__global__ void k_logits(const float* __restrict__ Z5, const float* __restrict__ abb5,
                         const float* __restrict__ lout, const float* __restrict__ outw,
                         const float* __restrict__ outb, float* __restrict__ out){
  __shared__ float of[576];
  int r = blockIdx.x;
  int tid = threadIdx.x;
  if (tid < 64) of[tid] = fmaxf(abb5[tid]*Z5[(size_t)r*64+tid] + abb5[64+tid], 0.f);
  for (int e=tid; e<512; e+=256) of[64+e] = fmaxf(lout[(size_t)r*512+e], 0.f);
  __syncthreads();
  int o = tid>>3, k0 = tid&7;
  if (o < Vv){
    float acc = 0.f;
    for (int k=k0; k<576; k+=8) acc = fmaf(of[k], outw[o*576+k], acc);
    acc += __shfl_xor(acc,1); acc += __shfl_xor(acc,2); acc += __shfl_xor(acc,4);
    if (k0==0) out[r*Vv + o] = acc + outb[o];
  }
}

extern "C" void kernel_launch(void* const* d_in, const int* in_sizes, int n_in,
                              void* d_out, int out_size, void* d_ws, size_t ws_size,
                              hipStream_t stream){
  (void)in_sizes; (void)n_in; (void)out_size; (void)ws_size;
  const float* L   = (const float*)d_in[0];
  const float* PL  = (const float*)d_in[1];
  const float* PI  = (const float*)d_in[2];
  const int*   AA  = (const int*)d_in[3];
  const float* H0  = (const float*)d_in[4];
  const float* C0  = (const float*)d_in[5];
  const float* DSF = (const float*)d_in[6];
  const float* W1  = (const float*)d_in[7];
  const float* W2  = (const float*)d_in[9];
  const float* W3  = (const float*)d_in[11];
  const float* FC1W= (const float*)d_in[13];
  const float* FC2W= (const float*)d_in[15];
  const float* G0=(const float*)d_in[17]; const float* Bt0=(const float*)d_in[18];
  const float* G1=(const float*)d_in[19]; const float* Bt1=(const float*)d_in[20];
  const float* G2=(const float*)d_in[21]; const float* Bt2=(const float*)d_in[22];
  const float* G3=(const float*)d_in[23]; const float* Bt3=(const float*)d_in[24];
  const float* G4=(const float*)d_in[25]; const float* Bt4=(const float*)d_in[26];
  const float* G5=(const float*)d_in[27]; const float* Bt5=(const float*)d_in[28];
  const float* EMB=(const float*)d_in[29];
  const float* WIH=(const float*)d_in[30];
  const float* WHH=(const float*)d_in[31];
  const float* BIH=(const float*)d_in[32];
  const float* BHH=(const float*)d_in[33];
  const float* OUTW=(const float*)d_in[34];
  const float* OUTB=(const float*)d_in[35];
  float* out = (float*)d_out;
  float* ws  = (float*)d_ws;

  size_t o = 0;
  unsigned short* Z1B = (unsigned short*)(ws+o); o += (size_t)Rr*32;   // Rr*64 bf16
  unsigned short* Z2B = (unsigned short*)(ws+o); o += (size_t)Rr*64;   // Rr*128 bf16
  float* PS0   = ws+o; o += 2*4096*CIN + 16;
  float* PS1   = ws+o; o += 2*NB1*64 + 16;
  float* PS2   = ws+o; o += 2*NB23*128 + 16;
  float* PS3   = ws+o; o += 2*NB23*256 + 16;
  float* PM3   = ws+o; o += NB23*2*256 + 16;
  float* PN3   = ws+o; o += NB23*2*256 + 16;
  float* ABB1  = ws+o; o += 128;
  float* ABB2  = ws+o; o += 256;
  float* ABB3  = ws+o; o += 512;
  float* ABB4  = ws+o; o += 256;
  float* ABB5  = ws+o; o += 128;
  unsigned short* W1B = (unsigned short*)(ws+o); o += 64*K1P/2 + 16;
  unsigned short* W2B = (unsigned short*)(ws+o); o += 4096 + 16;
  unsigned short* W3B = (unsigned short*)(ws+o); o += 16384 + 16;
  float* Z4    = ws+o; o += 65536;
  float* Z5    = ws+o; o += 32768;
  float* EMBW  = ws+o; o += 53248;
  float* HB0   = ws+o; o += 8192;
  float* HB1   = ws+o; o += 8192;
  float* CB    = ws+o; o += 8192;
  float* LOUT  = ws+o; o += 262144;

  // front: weight converts + W1B pad | embw dots | bn0 partial stats — single launch
  k_front<<<17580,256,0,stream>>>(W2,W3,EMB,WIH,BIH,BHH,L,PL,PI,DSF,W2B,W3B,W1B,EMBW,PS0);

  // point cloud branch
  k_reduce0<<<CIN,256,0,stream>>>(PS0,G0,W1,W1B);
  k_conv1mf<<<NB1,256,0,stream>>>(L,PL,PI,DSF,W1B,Z1B,PS1);
  k_reduce_ps<<<64,256,0,stream>>>(PS1, NB1, 64, 1.0f/(float)Rr, G1, Bt1, ABB1);
  k_convmf<<<NB23,256,0,stream>>>(Z1B,ABB1,W2B,Z2B,PS2,NB23);
  k_reduce_ps<<<128,256,0,stream>>>(PS2, NB23, 128, 1.0f/(float)Rr, G2, Bt2, ABB2);
  k_conv3mf<<<NB23,256,0,stream>>>(Z2B,ABB2,W3B,PS3,NB23,PM3,PN3);
  k_reduce_ps<<<256,256,0,stream>>>(PS3, NB23, 256, 1.0f/(float)Rr, G3, Bt3, ABB3);
  k_poolfc1<<<512,256,0,stream>>>(PM3,PN3,ABB3,FC1W,Z4);
  k_colstats_par<<<128,256,0,stream>>>(Z4,512,128,G4,Bt4,ABB4);
  k_fc<<<8192,256,0,stream>>>(Z4,FC2W,ABB4,Z5,64,128);
  k_colstats_par<<<64,256,0,stream>>>(Z5,512,64,G5,Bt5,ABB5);

  // LSTM branch — 32 step launches (init/out fused into steps 0/31)
  for (int t=0;t<32;t++){
    const float* hp = (t==0) ? H0 : ((t&1)?HB1:HB0);
    float* hn = (t&1)?HB0:HB1;
    const float* ci = (t==0) ? C0 : CB;
    float* outhc = (t==31) ? out : nullptr;
    k_lstm_step<<<512,256,0,stream>>>(hp,hn,ci,CB,EMBW,AA,WHH,LOUT,outhc,t);
  }

  // output head
  k_logits<<<512,256,0,stream>>>(Z5,ABB5,LOUT,OUTW,OUTB,out);
}

// Round 16
// 420.405 us; speedup vs baseline: 1.0591x; 1.0591x over previous
//
#include <hip/hip_runtime.h>
#include <hip/hip_bf16.h>
#include <math.h>

#define Bb 16
#define Tt 32
#define Vv 26
#define Nn 500
#define Uu 64
#define Hh 512
#define CIN 209
#define K1P 256
#define Mm 512
#define Rr 256000
#define NB1 4000
#define NB23 2000

typedef short short8 __attribute__((ext_vector_type(8)));
typedef float f32x4 __attribute__((ext_vector_type(4)));

__device__ __forceinline__ float sigf(float x){ return 1.0f/(1.0f+expf(-x)); }
__device__ __forceinline__ float frcp(float x){ return __builtin_amdgcn_rcpf(x); }
__device__ __forceinline__ unsigned short f2bf(float f){
  __hip_bfloat16 h = __float2bfloat16(f);
  return *reinterpret_cast<unsigned short*>(&h);
}
__device__ __forceinline__ float bf2f(unsigned short h){
  return __uint_as_float(((unsigned)h)<<16);
}

// ---------------- front fusion: wprep converts + W1B pad | embw dots | bn0 partial stats ----------------
__global__ void k_front(const float* __restrict__ W2, const float* __restrict__ W3,
                        const float* __restrict__ EMB, const float* __restrict__ WIH,
                        const float* __restrict__ BIH, const float* __restrict__ BHH,
                        const float* __restrict__ L, const float* __restrict__ PL,
                        const float* __restrict__ PI, const float* __restrict__ DSF,
                        unsigned short* __restrict__ W2B, unsigned short* __restrict__ W3B,
                        unsigned short* __restrict__ W1B,
                        float* __restrict__ embw, float* __restrict__ ps0){
  int bid = blockIdx.x;
  int tid = threadIdx.x;
  if (bid < 172){
    int idx = bid*256 + tid;
    if (idx < 8192){ W2B[idx] = f2bf(W2[idx]); return; }
    idx -= 8192;
    if (idx < 32768){ W3B[idx] = f2bf(W3[idx]); return; }
    idx -= 32768;
    if (idx < 3008){ int oo = idx/47, kk = 209 + idx - (idx/47)*47; W1B[oo*K1P + kk] = 0; }
    return;
  }
  if (bid < 13484){
    int gw = (bid-172)*4 + (tid>>6);
    int lane = tid & 63;
    int v = gw >> 11;
    int j = gw & 2047;
    const float4* ea = (const float4*)&EMB[(size_t)v*512];
    const float4* wa = (const float4*)&WIH[(size_t)j*512];
    float4 e0 = ea[lane*2], e1 = ea[lane*2+1];
    float4 w0 = wa[lane*2], w1 = wa[lane*2+1];
    float s = e0.x*w0.x + e0.y*w0.y + e0.z*w0.z + e0.w*w0.w
            + e1.x*w1.x + e1.y*w1.y + e1.z*w1.z + e1.w*w1.w;
    #pragma unroll
    for (int off=1; off<64; off<<=1) s += __shfl_xor(s,off);
    if (lane==0) embw[(size_t)v*2048 + j] = s + BIH[j] + BHH[j];
    return;
  }
  int fid = bid - 13484;
  int m = fid>>3, q = fid&7;
  int b = m >> 5;
  int n0 = q*62 + ((q<4)?q:4);
  int cnt = 62 + (q<4 ? 1 : 0);
  __shared__ float pl_sh[63], pi_sh[63];
  for (int n=tid; n<cnt; n+=256){ pl_sh[n]=PL[b*Nn+n0+n]; pi_sh[n]=PI[b*Nn+n0+n]; }
  __syncthreads();
  if (tid >= CIN) return;
  float sum=0.f, sq=0.f;
  if (tid < CIN-1){
    float li = L[m*208 + tid];
    if (li > 1e-5f){
      float cfac = sigf(DSF[0])*200000.0f;
      float si = frcp(li + 1e-6f)*cfac;
      for (int n=0;n<cnt;n++){
        float pl = pl_sh[n];
        float f = (pl > 1e-5f) ? __expf(-fabsf((pl-li)*si)) : 0.f;
        sum += f; sq += f*f;
      }
    }
  } else {
    for (int n=0;n<cnt;n++){ float v=pi_sh[n]; sum+=v; sq+=v*v; }
  }
  int pb = m*8+q;
  ps0[(size_t)pb*CIN + tid] = sum;
  ps0[(size_t)(4096+pb)*CIN + tid] = sq;
}

// bn0 reduce + fold into W1B column (bb0 cancels through bn1; only scale needed)
__global__ void k_reduce0(const float* __restrict__ ps, const float* __restrict__ g,
                          const float* __restrict__ w1, unsigned short* __restrict__ w1b){
  int c = blockIdx.x;
  int tid = threadIdx.x;
  float s=0.f, q=0.f;
  for (int nb=tid; nb<4096; nb+=256){
    s += ps[(size_t)nb*CIN + c];
    q += ps[(size_t)(4096+nb)*CIN + c];
  }
  #pragma unroll
  for (int off=1; off<64; off<<=1){ s += __shfl_xor(s,off); q += __shfl_xor(q,off); }
  __shared__ float rs[4], rq[4];
  __shared__ float a_sh;
  if ((tid&63)==0){ rs[tid>>6]=s; rq[tid>>6]=q; }
  __syncthreads();
  if (tid==0){
    s = rs[0]+rs[1]+rs[2]+rs[3]; q = rq[0]+rq[1]+rq[2]+rq[3];
    float mean = s/(float)Rr;
    float var  = q/(float)Rr - mean*mean;
    a_sh = g[c]*rsqrtf(var + 1e-5f);
  }
  __syncthreads();
  if (tid < 64) w1b[tid*K1P + c] = f2bf(w1[tid*CIN + c] * a_sh);
}

// per-channel reduce of per-block partials -> (a, bb)
__global__ void k_reduce_ps(const float* __restrict__ ps, int NB, int C, float invCount,
                            const float* __restrict__ g, const float* __restrict__ bt,
                            float* __restrict__ abb){
  int c = blockIdx.x;
  int tid = threadIdx.x;
  float s=0.f, q=0.f;
  for (int nb=tid; nb<NB; nb+=256){
    s += ps[(size_t)nb*C + c];
    q += ps[(size_t)(NB+nb)*C + c];
  }
  #pragma unroll
  for (int off=1; off<64; off<<=1){ s += __shfl_xor(s,off); q += __shfl_xor(q,off); }
  __shared__ float rs[4], rq[4];
  if ((tid&63)==0){ rs[tid>>6]=s; rq[tid>>6]=q; }
  __syncthreads();
  if (tid==0){
    s = rs[0]+rs[1]+rs[2]+rs[3]; q = rq[0]+rq[1]+rq[2]+rq[3];
    float mean = s*invCount;
    float var  = q*invCount - mean*mean;
    float istd = rsqrtf(var + 1e-5f);
    float a = g[c]*istd;
    abb[c] = a;
    abb[C+c] = bt[c] - mean*a;
  }
}

// parallel per-column mean/var over Mrows -> (a, bb); one block per column
__global__ void k_colstats_par(const float* __restrict__ Z, int Mrows, int C,
                               const float* __restrict__ g, const float* __restrict__ bt,
                               float* __restrict__ abb){
  int c = blockIdx.x;
  int tid = threadIdx.x;
  float s=0.f,q=0.f;
  for (int r=tid; r<Mrows; r+=256){ float v=Z[(size_t)r*C+c]; s+=v; q+=v*v; }
  #pragma unroll
  for (int off=1; off<64; off<<=1){ s += __shfl_xor(s,off); q += __shfl_xor(q,off); }
  __shared__ float rs[4], rq[4];
  if ((tid&63)==0){ rs[tid>>6]=s; rq[tid>>6]=q; }
  __syncthreads();
  if (tid==0){
    s = rs[0]+rs[1]+rs[2]+rs[3]; q = rq[0]+rq[1]+rq[2]+rq[3];
    float mean = s/(float)Mrows;
    float var  = q/(float)Mrows - mean*mean;
    float istd = rsqrtf(var + 1e-5f);
    float a = g[c]*istd;
    abb[c]=a; abb[C+c]=bt[c]-mean*a;
  }
}

// ---------------- conv1 MFMA: K-chunked (2x128); A and B staged in LDS ----------------
__launch_bounds__(256)
__global__ void k_conv1mf(const float* __restrict__ L, const float* __restrict__ PL,
                          const float* __restrict__ PI, const float* __restrict__ DSF,
                          const unsigned short* __restrict__ W1B,
                          unsigned short* __restrict__ Z1B, float* __restrict__ ps){
  __shared__ __align__(16) unsigned short Abuf[64*128];
  __shared__ __align__(16) unsigned short Bbuf[64*128];
  __shared__ __align__(16) float si_s[2][208];
  __shared__ float pl_s[64], pi_s[64];
  __shared__ int mi_i[64];
  __shared__ float red[4][2][64];
  int tid = threadIdx.x;
  int r0 = blockIdx.x*64;
  int m0 = r0/500, m1 = (r0+63)/500;
  float cfac = sigf(DSF[0])*200000.0f;
  if (tid < 64){
    int r = r0+tid; int m = r/500; int n = r - m*500; int b = m >> 5;
    pl_s[tid] = PL[b*Nn+n]; pi_s[tid] = PI[b*Nn+n]; mi_i[tid] = (m == m0) ? 0 : 1;
  }
  for (int j=tid; j<416; j+=256){
    int gg = (j>=208) ? 1 : 0; int jj = j - gg*208;
    float li = L[(size_t)(gg?m1:m0)*208 + jj];
    si_s[gg][jj] = (li > 1e-5f) ? frcp(li+1e-6f)*cfac : -1.0f;
  }
  int lane = tid&63, wid = tid>>6;
  int l15 = lane&15, lhi = lane>>4;
  int ar = wid*16 + l15;
  unsigned aswz = ((unsigned)(ar&7))<<4;
  f32x4 acc[4] = {};
  __syncthreads();
  for (int kc=0; kc<2; kc++){
    if (kc) __syncthreads();
    for (int e=tid; e<1024; e+=256){
      int row = e>>4; int k4 = (e&15)*8;
      short8 w = *(const short8*)&W1B[row*K1P + kc*128 + k4];
      unsigned byte = ((unsigned)(row*128 + k4))*2u ^ (((unsigned)(row&7))<<4);
      *(short8*)((char*)Bbuf + byte) = w;
    }
    for (int e=tid; e<1024; e+=256){
      int row = e>>4; int j0l = (e&15)*8;
      int jg = kc*128 + j0l;
      float pl = pl_s[row];
      bool plok = pl > 1e-5f;
      short8 st;
      if (jg < 208){
        int mi = mi_i[row];
        const float* lp = &L[(size_t)(mi?m1:m0)*208 + jg];
        float4 la = *(const float4*)lp;
        float4 lb = *(const float4*)(lp+4);
        float4 sa = *(const float4*)&si_s[mi][jg];
        float4 sb = *(const float4*)&si_s[mi][jg+4];
        float li[8] = {la.x,la.y,la.z,la.w,lb.x,lb.y,lb.z,lb.w};
        float si[8] = {sa.x,sa.y,sa.z,sa.w,sb.x,sb.y,sb.z,sb.w};
        #pragma unroll
        for (int j=0;j<8;j++){
          float v = (plok && si[j] >= 0.f) ? __expf(-fabsf((pl-li[j])*si[j])) : 0.f;
          st[j] = (short)f2bf(v);
        }
      } else {
        #pragma unroll
        for (int j=0;j<8;j++) st[j] = 0;
        if (jg == 208) st[0] = (short)f2bf(pi_s[row]);
      }
      unsigned byte = ((unsigned)(row*128 + j0l))*2u ^ (((unsigned)(row&7))<<4);
      *(short8*)((char*)Abuf + byte) = st;
    }
    __syncthreads();
    #pragma unroll
    for (int ks=0; ks<4; ks++){
      int kb = ks*32 + lhi*8;
      short8 af = *(const short8*)((const char*)Abuf + ((((unsigned)(ar*128 + kb))*2u) ^ aswz));
      #pragma unroll
      for (int fj=0; fj<4; fj++){
        int bc = fj*16 + l15;
        short8 bfv = *(const short8*)((const char*)Bbuf + ((((unsigned)(bc*128 + kb))*2u) ^ (((unsigned)(bc&7))<<4)));
        acc[fj] = __builtin_amdgcn_mfma_f32_16x16x32_bf16(af, bfv, acc[fj], 0, 0, 0);
      }
    }
  }
  #pragma unroll
  for (int fj=0; fj<4; fj++){
    int ch = fj*16 + l15;
    float s=0.f, q=0.f;
    #pragma unroll
    for (int qi=0; qi<4; qi++){
      float zv = acc[fj][qi];
      int rg = r0 + wid*16 + lhi*4 + qi;
      Z1B[(size_t)rg*Uu + ch] = f2bf(zv);
      s += zv; q = fmaf(zv,zv,q);
    }
    s += __shfl_xor(s,16); s += __shfl_xor(s,32);
    q += __shfl_xor(q,16); q += __shfl_xor(q,32);
    if (lhi == 0){ red[wid][0][ch]=s; red[wid][1][ch]=q; }
  }
  __syncthreads();
  if (tid < 64){
    float s = red[0][0][tid]+red[1][0][tid]+red[2][0][tid]+red[3][0][tid];
    float q = red[0][1][tid]+red[1][1][tid]+red[2][1][tid]+red[3][1][tid];
    ps[(size_t)blockIdx.x*Uu + tid] = s;
    ps[(size_t)(NB1 + blockIdx.x)*Uu + tid] = q;
  }
}

// ---------------- conv2 MFMA: A in LDS, B direct from L2 (1:4 B reuse) ----------------
__launch_bounds__(256,4)
__global__ void k_convmf(const unsigned short* __restrict__ Xin, const float* __restrict__ abbIn,
                         const unsigned short* __restrict__ Wb,
                         unsigned short* __restrict__ Zout,
                         float* __restrict__ ps, int NB){
  constexpr int K = 64, Ctot = 128;
  __shared__ __align__(16) unsigned short Abuf[128*K];
  __shared__ float abbs[2*K];
  __shared__ float redS[2][128], redQ[2][128];
  int tid = threadIdx.x;
  int r0 = blockIdx.x*128;
  for (int e=tid; e<2*K; e+=256) abbs[e] = abbIn[e];
  __syncthreads();
  constexpr int CPR = K/8;
  for (int e=tid; e<128*CPR; e+=256){
    int row = e/CPR; int kc = (e - row*CPR)*8;
    short8 rawv = *(const short8*)(Xin + (size_t)(r0+row)*K + kc);
    short8 st;
    #pragma unroll
    for (int j=0;j<8;j++){
      float t = fmaxf(abbs[kc+j]*bf2f((unsigned short)rawv[j]) + abbs[K+kc+j], 0.f);
      st[j] = (short)f2bf(t);
    }
    unsigned byte = ((unsigned)(row*K + kc))*2u; byte ^= ((unsigned)(row&7))<<4;
    *(short8*)((char*)Abuf + byte) = st;
  }
  __syncthreads();

  int lane = tid&63, wid = tid>>6;
  int wr = wid>>1, wc = wid&1;
  int l15 = lane&15, lhi = lane>>4;
  f32x4 acc[4][4] = {};
  #pragma unroll
  for (int ks=0; ks<K/32; ks++){
    short8 af[4], bfr[4];
    int kb = ks*32 + lhi*8;
    #pragma unroll
    for (int f=0; f<4; f++){
      int arr = wr*64 + f*16 + l15;
      unsigned ab = ((unsigned)(arr*K + kb))*2u ^ (((unsigned)(arr&7))<<4);
      af[f] = *(const short8*)((const char*)Abuf + ab);
      int bc = wc*64 + f*16 + l15;
      bfr[f] = *(const short8*)&Wb[(size_t)bc*K + kb];
    }
    #pragma unroll
    for (int fi=0; fi<4; fi++)
      #pragma unroll
      for (int fj=0; fj<4; fj++)
        acc[fi][fj] = __builtin_amdgcn_mfma_f32_16x16x32_bf16(af[fi], bfr[fj], acc[fi][fj], 0, 0, 0);
  }

  #pragma unroll
  for (int fj=0; fj<4; fj++){
    int cg = wc*64 + fj*16 + l15;
    float s=0.f, q=0.f;
    #pragma unroll
    for (int fi=0; fi<4; fi++){
      #pragma unroll
      for (int qi=0; qi<4; qi++){
        float zv = acc[fi][fj][qi];
        int rg = r0 + wr*64 + fi*16 + lhi*4 + qi;
        Zout[(size_t)rg*Ctot + cg] = f2bf(zv);
        s += zv; q = fmaf(zv,zv,q);
      }
    }
    s += __shfl_xor(s,16); s += __shfl_xor(s,32);
    q += __shfl_xor(q,16); q += __shfl_xor(q,32);
    if (lhi == 0){ redS[wr][cg]=s; redQ[wr][cg]=q; }
  }
  __syncthreads();
  if (tid < 128){
    float s = redS[0][tid]+redS[1][tid];
    float q = redQ[0][tid]+redQ[1][tid];
    size_t ci = (size_t)blockIdx.x*Ctot + tid;
    ps[ci] = s;
    ps[(size_t)NB*Ctot + ci] = q;
  }
}

// ---------------- conv3 MFMA: A in LDS once, B direct from L2, 2 col-halves ----------------
__launch_bounds__(256,3)
__global__ void k_conv3mf(const unsigned short* __restrict__ Xin, const float* __restrict__ abbIn,
                          const unsigned short* __restrict__ Wb,
                          float* __restrict__ ps, int NB,
                          float* __restrict__ pm, float* __restrict__ pn){
  constexpr int K = 128, Ctot = 256;
  __shared__ __align__(16) unsigned short Abuf[128*K];
  __shared__ float abbs[2*K];
  __shared__ float redS[2][128], redQ[2][128];
  __shared__ float mxS[2][2][128], mnS[2][2][128];
  int tid = threadIdx.x;
  int r0 = blockIdx.x*128;
  for (int e=tid; e<2*K; e+=256) abbs[e] = abbIn[e];
  __syncthreads();
  constexpr int CPR = K/8;
  for (int e=tid; e<128*CPR; e+=256){
    int row = e/CPR; int kc = (e - row*CPR)*8;
    short8 rawv = *(const short8*)(Xin + (size_t)(r0+row)*K + kc);
    short8 st;
    #pragma unroll
    for (int j=0;j<8;j++){
      float t = fmaxf(abbs[kc+j]*bf2f((unsigned short)rawv[j]) + abbs[K+kc+j], 0.f);
      st[j] = (short)f2bf(t);
    }
    unsigned byte = ((unsigned)(row*K + kc))*2u; byte ^= ((unsigned)(row&7))<<4;
    *(short8*)((char*)Abuf + byte) = st;
  }
  __syncthreads();

  int lane = tid&63, wid = tid>>6;
  int wr = wid>>1, wc = wid&1;
  int l15 = lane&15, lhi = lane>>4;
  int m0 = r0/500;
  int mhi = (m0+1)*500;
  bool onem = (r0+127) < mhi;

  for (int half=0; half<2; half++){
    int c0 = half*128;
    if (half) __syncthreads();   // redS/mxS reuse

    f32x4 acc[4][4] = {};
    #pragma unroll
    for (int ks=0; ks<K/32; ks++){
      short8 af[4], bfr[4];
      int kb = ks*32 + lhi*8;
      #pragma unroll
      for (int f=0; f<4; f++){
        int arr = wr*64 + f*16 + l15;
        unsigned ab = ((unsigned)(arr*K + kb))*2u ^ (((unsigned)(arr&7))<<4);
        af[f] = *(const short8*)((const char*)Abuf + ab);
        int bc = c0 + wc*64 + f*16 + l15;
        bfr[f] = *(const short8*)&Wb[(size_t)bc*K + kb];
      }
      #pragma unroll
      for (int fi=0; fi<4; fi++)
        #pragma unroll
        for (int fj=0; fj<4; fj++)
          acc[fi][fj] = __builtin_amdgcn_mfma_f32_16x16x32_bf16(af[fi], bfr[fj], acc[fi][fj], 0, 0, 0);
    }

    if (onem){
      #pragma unroll
      for (int fj=0; fj<4; fj++){
        float s=0.f, q=0.f, mx0=-INFINITY, mn0=INFINITY;
        #pragma unroll
        for (int fi=0; fi<4; fi++){
          #pragma unroll
          for (int qi=0; qi<4; qi++){
            float zv = acc[fi][fj][qi];
            s += zv; q = fmaf(zv,zv,q);
            mx0 = fmaxf(mx0,zv); mn0 = fminf(mn0,zv);
          }
        }
        s += __shfl_xor(s,16); s += __shfl_xor(s,32);
        q += __shfl_xor(q,16); q += __shfl_xor(q,32);
        mx0 = fmaxf(mx0, __shfl_xor(mx0,16)); mx0 = fmaxf(mx0, __shfl_xor(mx0,32));
        mn0 = fminf(mn0, __shfl_xor(mn0,16)); mn0 = fminf(mn0, __shfl_xor(mn0,32));
        if (lhi == 0){
          int ch = wc*64 + fj*16 + l15;
          redS[wr][ch]=s; redQ[wr][ch]=q;
          mxS[wr][0][ch]=mx0; mxS[wr][1][ch]=-INFINITY;
          mnS[wr][0][ch]=mn0; mnS[wr][1][ch]=INFINITY;
        }
      }
    } else {
      #pragma unroll
      for (int fj=0; fj<4; fj++){
        float s=0.f, q=0.f;
        float mx0=-INFINITY,mx1=-INFINITY,mn0=INFINITY,mn1=INFINITY;
        #pragma unroll
        for (int fi=0; fi<4; fi++){
          #pragma unroll
          for (int qi=0; qi<4; qi++){
            float zv = acc[fi][fj][qi];
            int rg = r0 + wr*64 + fi*16 + lhi*4 + qi;
            s += zv; q = fmaf(zv,zv,q);
            if (rg >= mhi){ mx1=fmaxf(mx1,zv); mn1=fminf(mn1,zv); }
            else          { mx0=fmaxf(mx0,zv); mn0=fminf(mn0,zv); }
          }
        }
        s += __shfl_xor(s,16); s += __shfl_xor(s,32);
        q += __shfl_xor(q,16); q += __shfl_xor(q,32);
        mx0 = fmaxf(mx0, __shfl_xor(mx0,16)); mx0 = fmaxf(mx0, __shfl_xor(mx0,32));
        mx1 = fmaxf(mx1, __shfl_xor(mx1,16)); mx1 = fmaxf(mx1, __shfl_xor(mx1,32));
        mn0 = fminf(mn0, __shfl_xor(mn0,16)); mn0 = fminf(mn0, __shfl_xor(mn0,32));
        mn1 = fminf(mn1, __shfl_xor(mn1,16)); mn1 = fminf(mn1, __shfl_xor(mn1,32));
        if (lhi == 0){
          int ch = wc*64 + fj*16 + l15;
          redS[wr][ch]=s; redQ[wr][ch]=q;
          mxS[wr][0][ch]=mx0; mxS[wr][1][ch]=mx1;
          mnS[wr][0][ch]=mn0; mnS[wr][1][ch]=mn1;
        }
      }
    }
    __syncthreads();
    if (tid < 128){
      float s = redS[0][tid]+redS[1][tid];
      float q = redQ[0][tid]+redQ[1][tid];
      size_t ci = (size_t)blockIdx.x*Ctot + c0 + tid;
      ps[ci] = s;
      ps[(size_t)NB*Ctot + ci] = q;
      #pragma unroll
      for (int g=0; g<2; g++){
        pm[((size_t)blockIdx.x*2+g)*Ctot + c0 + tid] = fmaxf(mxS[0][g][tid], mxS[1][g][tid]);
        pn[((size_t)blockIdx.x*2+g)*Ctot + c0 + tid] = fminf(mnS[0][g][tid], mnS[1][g][tid]);
      }
    }
  }
}

// ---------------- fused pool + FC1: one block per output row ----------------
__launch_bounds__(256)
__global__ void k_poolfc1(const float* __restrict__ pm, const float* __restrict__ pn,
                          const float* __restrict__ abb3, const float* __restrict__ FC1W,
                          float* __restrict__ Z4){
  __shared__ float of[256];
  int r = blockIdx.x;
  int tid = threadIdx.x;
  {
    int c = tid;
    int bxlo = (500*r)/128;
    int bxhi = (500*r+499)/128;
    float mx=-INFINITY, mn=INFINITY;
    for (int bx=bxlo; bx<=bxhi; bx++){
      int mb = (bx*128)/500;
      int gg = r - mb;
      if (gg==0 || gg==1){
        mx = fmaxf(mx, pm[((size_t)bx*2+gg)*256 + c]);
        mn = fminf(mn, pn[((size_t)bx*2+gg)*256 + c]);
      }
    }
    float a = abb3[c], bb = abb3[256+c];
    float zv = (a >= 0.f) ? mx : mn;
    of[c] = fmaxf(a*zv + bb, 0.f);
  }
  __syncthreads();
  if (tid < 128){
    float acc = 0.f;
    const float* wr = &FC1W[(size_t)tid*256];
    #pragma unroll 4
    for (int k=0;k<256;k++) acc = fmaf(of[k], wr[k], acc);
    Z4[(size_t)r*128 + tid] = acc;
  }
}

// ---------------- FC2: wave per output ----------------
__launch_bounds__(256)
__global__ void k_fc(const float* __restrict__ A, const float* __restrict__ W,
                     const float* __restrict__ abb, float* __restrict__ C,
                     int Ncols, int K){
  int gw = blockIdx.x*4 + (threadIdx.x>>6);
  int lane = threadIdx.x & 63;
  int r = gw / Ncols, c = gw - r*Ncols;
  float s = 0.f;
  for (int k=lane; k<K; k+=64){
    float v = A[(size_t)r*K + k];
    if (abb) v = fmaxf(abb[k]*v + abb[K+k], 0.f);
    s = fmaf(v, W[(size_t)c*K + k], s);
  }
  #pragma unroll
  for (int off=1; off<64; off<<=1) s += __shfl_xor(s,off);
  if (lane==0) C[(size_t)r*Ncols + c] = s;
}

// one LSTM step; 512 blocks (one u-column each) x 256 thr; wave = gate, lane = (seg,b)
__launch_bounds__(256)
__global__ void k_lstm_step(const float* __restrict__ hprev, float* __restrict__ hnext,
                            const float* __restrict__ cin, float* __restrict__ cout,
                            const float* __restrict__ embw, const int* __restrict__ aa,
                            const float* __restrict__ whh, float* __restrict__ lout,
                            float* __restrict__ outhc, int t){
  __shared__ float h_s[16][516];
  __shared__ float g_s[4][16];
  int tid = threadIdx.x;
  int u = blockIdx.x;
  for (int e=tid; e<2048; e+=256){
    int idx = e*4;
    *(float4*)&h_s[idx>>9][idx&511] = *(const float4*)&hprev[idx];
  }
  __syncthreads();
  int w = tid>>6, lane = tid&63;
  int seg = lane>>4, b = lane&15;
  int j = w*512 + u;
  const float4* wrow = (const float4*)&whh[(size_t)j*512] + seg*32;
  const float4* hrow = (const float4*)&h_s[b][0] + seg*32;
  float a0=0.f, a1=0.f, a2=0.f, a3=0.f;
  #pragma unroll 4
  for (int k=0;k<32;k++){
    float4 wv = wrow[k]; float4 hv = hrow[k];
    a0 = fmaf(hv.x,wv.x,a0); a1 = fmaf(hv.y,wv.y,a1);
    a2 = fmaf(hv.z,wv.z,a2); a3 = fmaf(hv.w,wv.w,a3);
  }
  float s = (a0+a1)+(a2+a3);
  s += __shfl_xor(s,16);
  s += __shfl_xor(s,32);
  if (lane < 16){
    int v = aa[lane*Tt + t];
    g_s[w][lane] = s + embw[(size_t)v*2048 + j];
  }
  __syncthreads();
  if (tid < 16){
    int b2 = tid;
    float iv = g_s[0][b2], fv = g_s[1][b2], gv = g_s[2][b2], ov = g_s[3][b2];
    int ci = b2*512 + u;
    float cn = sigf(fv)*cin[ci] + sigf(iv)*tanhf(gv);
    float hn = sigf(ov)*tanhf(cn);
    cout[ci]=cn; hnext[ci]=hn;
    lout[(size_t)(b2*Tt + t)*Hh + u] = hn;
    if (outhc){ outhc[Mm*Vv + ci] = hn; outhc[Mm*Vv + Bb*Hh + ci] = cn; }
  }
}

// logits: one block per output row; 8-lane dot groups over 26 outputs
__launch_bounds__(256)
__global__ void k_logits(const float* __restrict__ Z5, const float* __restrict__ abb5,
                         const float* __restrict__ lout, const float* __restrict__ outw,
                         const float* __restrict__ outb, float* __restrict__ out){
  __shared__ float of[576];
  int r = blockIdx.x;
  int tid = threadIdx.x;
  if (tid < 64) of[tid] = fmaxf(abb5[tid]*Z5[(size_t)r*64+tid] + abb5[64+tid], 0.f);
  for (int e=tid; e<512; e+=256) of[64+e] = fmaxf(lout[(size_t)r*512+e], 0.f);
  __syncthreads();
  int o = tid>>3, k0 = tid&7;
  if (o < Vv){
    float acc = 0.f;
    for (int k=k0; k<576; k+=8) acc = fmaf(of[k], outw[o*576+k], acc);
    acc += __shfl_xor(acc,1); acc += __shfl_xor(acc,2); acc += __shfl_xor(acc,4);
    if (k0==0) out[r*Vv + o] = acc + outb[o];
  }
}

extern "C" void kernel_launch(void* const* d_in, const int* in_sizes, int n_in,
                              void* d_out, int out_size, void* d_ws, size_t ws_size,
                              hipStream_t stream){
  (void)in_sizes; (void)n_in; (void)out_size; (void)ws_size;
  const float* L   = (const float*)d_in[0];
  const float* PL  = (const float*)d_in[1];
  const float* PI  = (const float*)d_in[2];
  const int*   AA  = (const int*)d_in[3];
  const float* H0  = (const float*)d_in[4];
  const float* C0  = (const float*)d_in[5];
  const float* DSF = (const float*)d_in[6];
  const float* W1  = (const float*)d_in[7];
  const float* W2  = (const float*)d_in[9];
  const float* W3  = (const float*)d_in[11];
  const float* FC1W= (const float*)d_in[13];
  const float* FC2W= (const float*)d_in[15];
  const float* G0=(const float*)d_in[17]; const float* Bt0=(const float*)d_in[18];
  const float* G1=(const float*)d_in[19]; const float* Bt1=(const float*)d_in[20];
  const float* G2=(const float*)d_in[21]; const float* Bt2=(const float*)d_in[22];
  const float* G3=(const float*)d_in[23]; const float* Bt3=(const float*)d_in[24];
  const float* G4=(const float*)d_in[25]; const float* Bt4=(const float*)d_in[26];
  const float* G5=(const float*)d_in[27]; const float* Bt5=(const float*)d_in[28];
  const float* EMB=(const float*)d_in[29];
  const float* WIH=(const float*)d_in[30];
  const float* WHH=(const float*)d_in[31];
  const float* BIH=(const float*)d_in[32];
  const float* BHH=(const float*)d_in[33];
  const float* OUTW=(const float*)d_in[34];
  const float* OUTB=(const float*)d_in[35];
  float* out = (float*)d_out;
  float* ws  = (float*)d_ws;

  size_t o = 0;
  unsigned short* Z1B = (unsigned short*)(ws+o); o += (size_t)Rr*32;   // Rr*64 bf16
  unsigned short* Z2B = (unsigned short*)(ws+o); o += (size_t)Rr*64;   // Rr*128 bf16
  float* PS0   = ws+o; o += 2*4096*CIN + 16;
  float* PS1   = ws+o; o += 2*NB1*64 + 16;
  float* PS2   = ws+o; o += 2*NB23*128 + 16;
  float* PS3   = ws+o; o += 2*NB23*256 + 16;
  float* PM3   = ws+o; o += NB23*2*256 + 16;
  float* PN3   = ws+o; o += NB23*2*256 + 16;
  float* ABB1  = ws+o; o += 128;
  float* ABB2  = ws+o; o += 256;
  float* ABB3  = ws+o; o += 512;
  float* ABB4  = ws+o; o += 256;
  float* ABB5  = ws+o; o += 128;
  unsigned short* W1B = (unsigned short*)(ws+o); o += 64*K1P/2 + 16;
  unsigned short* W2B = (unsigned short*)(ws+o); o += 4096 + 16;
  unsigned short* W3B = (unsigned short*)(ws+o); o += 16384 + 16;
  float* Z4    = ws+o; o += 65536;
  float* Z5    = ws+o; o += 32768;
  float* EMBW  = ws+o; o += 53248;
  float* HB0   = ws+o; o += 8192;
  float* HB1   = ws+o; o += 8192;
  float* CB    = ws+o; o += 8192;
  float* LOUT  = ws+o; o += 262144;

  // front: weight converts + W1B pad | embw dots | bn0 partial stats — single launch
  k_front<<<17580,256,0,stream>>>(W2,W3,EMB,WIH,BIH,BHH,L,PL,PI,DSF,W2B,W3B,W1B,EMBW,PS0);

  // point cloud branch
  k_reduce0<<<CIN,256,0,stream>>>(PS0,G0,W1,W1B);
  k_conv1mf<<<NB1,256,0,stream>>>(L,PL,PI,DSF,W1B,Z1B,PS1);
  k_reduce_ps<<<64,256,0,stream>>>(PS1, NB1, 64, 1.0f/(float)Rr, G1, Bt1, ABB1);
  k_convmf<<<NB23,256,0,stream>>>(Z1B,ABB1,W2B,Z2B,PS2,NB23);
  k_reduce_ps<<<128,256,0,stream>>>(PS2, NB23, 128, 1.0f/(float)Rr, G2, Bt2, ABB2);
  k_conv3mf<<<NB23,256,0,stream>>>(Z2B,ABB2,W3B,PS3,NB23,PM3,PN3);
  k_reduce_ps<<<256,256,0,stream>>>(PS3, NB23, 256, 1.0f/(float)Rr, G3, Bt3, ABB3);
  k_poolfc1<<<512,256,0,stream>>>(PM3,PN3,ABB3,FC1W,Z4);
  k_colstats_par<<<128,256,0,stream>>>(Z4,512,128,G4,Bt4,ABB4);
  k_fc<<<8192,256,0,stream>>>(Z4,FC2W,ABB4,Z5,64,128);
  k_colstats_par<<<64,256,0,stream>>>(Z5,512,64,G5,Bt5,ABB5);

  // LSTM branch — 32 step launches (init/out fused into steps 0/31)
  for (int t=0;t<32;t++){
    const float* hp = (t==0) ? H0 : ((t&1)?HB1:HB0);
    float* hn = (t&1)?HB0:HB1;
    const float* ci = (t==0) ? C0 : CB;
    float* outhc = (t==31) ? out : nullptr;
    k_lstm_step<<<512,256,0,stream>>>(hp,hn,ci,CB,EMBW,AA,WHH,LOUT,outhc,t);
  }

  // output head
  k_logits<<<512,256,0,stream>>>(Z5,ABB5,LOUT,OUTW,OUTB,out);
}

// Round 17
// 391.198 us; speedup vs baseline: 1.1382x; 1.0747x over previous
//
#include <hip/hip_runtime.h>
#include <hip/hip_bf16.h>
#include <math.h>

#define Bb 16
#define Tt 32
#define Vv 26
#define Nn 500
#define Uu 64
#define Hh 512
#define CIN 209
#define K1P 256
#define Mm 512
#define Rr 256000
#define NB1 4000
#define NB23 2000

typedef short short8 __attribute__((ext_vector_type(8)));
typedef float f32x4 __attribute__((ext_vector_type(4)));

__device__ __forceinline__ float sigf(float x){ return 1.0f/(1.0f+expf(-x)); }
__device__ __forceinline__ float frcp(float x){ return __builtin_amdgcn_rcpf(x); }
__device__ __forceinline__ unsigned short f2bf(float f){
  __hip_bfloat16 h = __float2bfloat16(f);
  return *reinterpret_cast<unsigned short*>(&h);
}
__device__ __forceinline__ float bf2f(unsigned short h){
  return __uint_as_float(((unsigned)h)<<16);
}

// ---------------- front fusion: converts (W2,W3,W1B pad, WHH->bf16) | embw dots | bn0 stats ----------------
__global__ void k_front(const float* __restrict__ W2, const float* __restrict__ W3,
                        const float* __restrict__ WHH,
                        const float* __restrict__ EMB, const float* __restrict__ WIH,
                        const float* __restrict__ BIH, const float* __restrict__ BHH,
                        const float* __restrict__ L, const float* __restrict__ PL,
                        const float* __restrict__ PI, const float* __restrict__ DSF,
                        unsigned short* __restrict__ W2B, unsigned short* __restrict__ W3B,
                        unsigned short* __restrict__ W1B, unsigned short* __restrict__ WHHB,
                        float* __restrict__ embw, float* __restrict__ ps0){
  int bid = blockIdx.x;
  int tid = threadIdx.x;
  if (bid < 4268){
    int idx = bid*256 + tid;
    if (idx < 8192){ W2B[idx] = f2bf(W2[idx]); return; }
    idx -= 8192;
    if (idx < 32768){ W3B[idx] = f2bf(W3[idx]); return; }
    idx -= 32768;
    if (idx < 3008){ int oo = idx/47, kk = 209 + idx - (idx/47)*47; W1B[oo*K1P + kk] = 0; return; }
    idx -= 3008;
    if (idx < 1048576){ WHHB[idx] = f2bf(WHH[idx]); }
    return;
  }
  if (bid < 17580){
    int gw = (bid-4268)*4 + (tid>>6);
    int lane = tid & 63;
    int v = gw >> 11;
    int j = gw & 2047;
    const float4* ea = (const float4*)&EMB[(size_t)v*512];
    const float4* wa = (const float4*)&WIH[(size_t)j*512];
    float4 e0 = ea[lane*2], e1 = ea[lane*2+1];
    float4 w0 = wa[lane*2], w1 = wa[lane*2+1];
    float s = e0.x*w0.x + e0.y*w0.y + e0.z*w0.z + e0.w*w0.w
            + e1.x*w1.x + e1.y*w1.y + e1.z*w1.z + e1.w*w1.w;
    #pragma unroll
    for (int off=1; off<64; off<<=1) s += __shfl_xor(s,off);
    if (lane==0) embw[(size_t)v*2048 + j] = s + BIH[j] + BHH[j];
    return;
  }
  int fid = bid - 17580;
  int m = fid>>3, q = fid&7;
  int b = m >> 5;
  int n0 = q*62 + ((q<4)?q:4);
  int cnt = 62 + (q<4 ? 1 : 0);
  __shared__ float pl_sh[63], pi_sh[63];
  for (int n=tid; n<cnt; n+=256){ pl_sh[n]=PL[b*Nn+n0+n]; pi_sh[n]=PI[b*Nn+n0+n]; }
  __syncthreads();
  if (tid >= CIN) return;
  float sum=0.f, sq=0.f;
  if (tid < CIN-1){
    float li = L[m*208 + tid];
    if (li > 1e-5f){
      float cfac = sigf(DSF[0])*200000.0f;
      float si = frcp(li + 1e-6f)*cfac;
      for (int n=0;n<cnt;n++){
        float pl = pl_sh[n];
        float f = (pl > 1e-5f) ? __expf(-fabsf((pl-li)*si)) : 0.f;
        sum += f; sq += f*f;
      }
    }
  } else {
    for (int n=0;n<cnt;n++){ float v=pi_sh[n]; sum+=v; sq+=v*v; }
  }
  int pb = m*8+q;
  ps0[(size_t)pb*CIN + tid] = sum;
  ps0[(size_t)(4096+pb)*CIN + tid] = sq;
}

// bn0 reduce + fold into W1B column (bb0 cancels through bn1; only scale needed)
__global__ void k_reduce0(const float* __restrict__ ps, const float* __restrict__ g,
                          const float* __restrict__ w1, unsigned short* __restrict__ w1b){
  int c = blockIdx.x;
  int tid = threadIdx.x;
  float s=0.f, q=0.f;
  for (int nb=tid; nb<4096; nb+=256){
    s += ps[(size_t)nb*CIN + c];
    q += ps[(size_t)(4096+nb)*CIN + c];
  }
  #pragma unroll
  for (int off=1; off<64; off<<=1){ s += __shfl_xor(s,off); q += __shfl_xor(q,off); }
  __shared__ float rs[4], rq[4];
  __shared__ float a_sh;
  if ((tid&63)==0){ rs[tid>>6]=s; rq[tid>>6]=q; }
  __syncthreads();
  if (tid==0){
    s = rs[0]+rs[1]+rs[2]+rs[3]; q = rq[0]+rq[1]+rq[2]+rq[3];
    float mean = s/(float)Rr;
    float var  = q/(float)Rr - mean*mean;
    a_sh = g[c]*rsqrtf(var + 1e-5f);
  }
  __syncthreads();
  if (tid < 64) w1b[tid*K1P + c] = f2bf(w1[tid*CIN + c] * a_sh);
}

// per-channel reduce of per-block partials -> (a, bb)
__global__ void k_reduce_ps(const float* __restrict__ ps, int NB, int C, float invCount,
                            const float* __restrict__ g, const float* __restrict__ bt,
                            float* __restrict__ abb){
  int c = blockIdx.x;
  int tid = threadIdx.x;
  float s=0.f, q=0.f;
  for (int nb=tid; nb<NB; nb+=256){
    s += ps[(size_t)nb*C + c];
    q += ps[(size_t)(NB+nb)*C + c];
  }
  #pragma unroll
  for (int off=1; off<64; off<<=1){ s += __shfl_xor(s,off); q += __shfl_xor(q,off); }
  __shared__ float rs[4], rq[4];
  if ((tid&63)==0){ rs[tid>>6]=s; rq[tid>>6]=q; }
  __syncthreads();
  if (tid==0){
    s = rs[0]+rs[1]+rs[2]+rs[3]; q = rq[0]+rq[1]+rq[2]+rq[3];
    float mean = s*invCount;
    float var  = q*invCount - mean*mean;
    float istd = rsqrtf(var + 1e-5f);
    float a = g[c]*istd;
    abb[c] = a;
    abb[C+c] = bt[c] - mean*a;
  }
}

// parallel per-column mean/var over Mrows -> (a, bb); one block per column
__global__ void k_colstats_par(const float* __restrict__ Z, int Mrows, int C,
                               const float* __restrict__ g, const float* __restrict__ bt,
                               float* __restrict__ abb){
  int c = blockIdx.x;
  int tid = threadIdx.x;
  float s=0.f,q=0.f;
  for (int r=tid; r<Mrows; r+=256){ float v=Z[(size_t)r*C+c]; s+=v; q+=v*v; }
  #pragma unroll
  for (int off=1; off<64; off<<=1){ s += __shfl_xor(s,off); q += __shfl_xor(q,off); }
  __shared__ float rs[4], rq[4];
  if ((tid&63)==0){ rs[tid>>6]=s; rq[tid>>6]=q; }
  __syncthreads();
  if (tid==0){
    s = rs[0]+rs[1]+rs[2]+rs[3]; q = rq[0]+rq[1]+rq[2]+rq[3];
    float mean = s/(float)Mrows;
    float var  = q/(float)Mrows - mean*mean;
    float istd = rsqrtf(var + 1e-5f);
    float a = g[c]*istd;
    abb[c]=a; abb[C+c]=bt[c]-mean*a;
  }
}

// ---------------- conv1 MFMA: K-chunked (2x128); A and B staged in LDS ----------------
__launch_bounds__(256)
__global__ void k_conv1mf(const float* __restrict__ L, const float* __restrict__ PL,
                          const float* __restrict__ PI, const float* __restrict__ DSF,
                          const unsigned short* __restrict__ W1B,
                          unsigned short* __restrict__ Z1B, float* __restrict__ ps){
  __shared__ __align__(16) unsigned short Abuf[64*128];
  __shared__ __align__(16) unsigned short Bbuf[64*128];
  __shared__ __align__(16) float si_s[2][208];
  __shared__ float pl_s[64], pi_s[64];
  __shared__ int mi_i[64];
  __shared__ float red[4][2][64];
  int tid = threadIdx.x;
  int r0 = blockIdx.x*64;
  int m0 = r0/500, m1 = (r0+63)/500;
  float cfac = sigf(DSF[0])*200000.0f;
  if (tid < 64){
    int r = r0+tid; int m = r/500; int n = r - m*500; int b = m >> 5;
    pl_s[tid] = PL[b*Nn+n]; pi_s[tid] = PI[b*Nn+n]; mi_i[tid] = (m == m0) ? 0 : 1;
  }
  for (int j=tid; j<416; j+=256){
    int gg = (j>=208) ? 1 : 0; int jj = j - gg*208;
    float li = L[(size_t)(gg?m1:m0)*208 + jj];
    si_s[gg][jj] = (li > 1e-5f) ? frcp(li+1e-6f)*cfac : -1.0f;
  }
  int lane = tid&63, wid = tid>>6;
  int l15 = lane&15, lhi = lane>>4;
  int ar = wid*16 + l15;
  unsigned aswz = ((unsigned)(ar&7))<<4;
  f32x4 acc[4] = {};
  __syncthreads();
  for (int kc=0; kc<2; kc++){
    if (kc) __syncthreads();
    for (int e=tid; e<1024; e+=256){
      int row = e>>4; int k4 = (e&15)*8;
      short8 w = *(const short8*)&W1B[row*K1P + kc*128 + k4];
      unsigned byte = ((unsigned)(row*128 + k4))*2u ^ (((unsigned)(row&7))<<4);
      *(short8*)((char*)Bbuf + byte) = w;
    }
    for (int e=tid; e<1024; e+=256){
      int row = e>>4; int j0l = (e&15)*8;
      int jg = kc*128 + j0l;
      float pl = pl_s[row];
      bool plok = pl > 1e-5f;
      short8 st;
      if (jg < 208){
        int mi = mi_i[row];
        const float* lp = &L[(size_t)(mi?m1:m0)*208 + jg];
        float4 la = *(const float4*)lp;
        float4 lb = *(const float4*)(lp+4);
        float4 sa = *(const float4*)&si_s[mi][jg];
        float4 sb = *(const float4*)&si_s[mi][jg+4];
        float li[8] = {la.x,la.y,la.z,la.w,lb.x,lb.y,lb.z,lb.w};
        float si[8] = {sa.x,sa.y,sa.z,sa.w,sb.x,sb.y,sb.z,sb.w};
        #pragma unroll
        for (int j=0;j<8;j++){
          float v = (plok && si[j] >= 0.f) ? __expf(-fabsf((pl-li[j])*si[j])) : 0.f;
          st[j] = (short)f2bf(v);
        }
      } else {
        #pragma unroll
        for (int j=0;j<8;j++) st[j] = 0;
        if (jg == 208) st[0] = (short)f2bf(pi_s[row]);
      }
      unsigned byte = ((unsigned)(row*128 + j0l))*2u ^ (((unsigned)(row&7))<<4);
      *(short8*)((char*)Abuf + byte) = st;
    }
    __syncthreads();
    #pragma unroll
    for (int ks=0; ks<4; ks++){
      int kb = ks*32 + lhi*8;
      short8 af = *(const short8*)((const char*)Abuf + ((((unsigned)(ar*128 + kb))*2u) ^ aswz));
      #pragma unroll
      for (int fj=0; fj<4; fj++){
        int bc = fj*16 + l15;
        short8 bfv = *(const short8*)((const char*)Bbuf + ((((unsigned)(bc*128 + kb))*2u) ^ (((unsigned)(bc&7))<<4)));
        acc[fj] = __builtin_amdgcn_mfma_f32_16x16x32_bf16(af, bfv, acc[fj], 0, 0, 0);
      }
    }
  }
  #pragma unroll
  for (int fj=0; fj<4; fj++){
    int ch = fj*16 + l15;
    float s=0.f, q=0.f;
    #pragma unroll
    for (int qi=0; qi<4; qi++){
      float zv = acc[fj][qi];
      int rg = r0 + wid*16 + lhi*4 + qi;
      Z1B[(size_t)rg*Uu + ch] = f2bf(zv);
      s += zv; q = fmaf(zv,zv,q);
    }
    s += __shfl_xor(s,16); s += __shfl_xor(s,32);
    q += __shfl_xor(q,16); q += __shfl_xor(q,32);
    if (lhi == 0){ red[wid][0][ch]=s; red[wid][1][ch]=q; }
  }
  __syncthreads();
  if (tid < 64){
    float s = red[0][0][tid]+red[1][0][tid]+red[2][0][tid]+red[3][0][tid];
    float q = red[0][1][tid]+red[1][1][tid]+red[2][1][tid]+red[3][1][tid];
    ps[(size_t)blockIdx.x*Uu + tid] = s;
    ps[(size_t)(NB1 + blockIdx.x)*Uu + tid] = q;
  }
}

// ---------------- conv2 MFMA: A in LDS, B direct from L2 (1:4 B reuse) ----------------
__launch_bounds__(256,4)
__global__ void k_convmf(const unsigned short* __restrict__ Xin, const float* __restrict__ abbIn,
                         const unsigned short* __restrict__ Wb,
                         unsigned short* __restrict__ Zout,
                         float* __restrict__ ps, int NB){
  constexpr int K = 64, Ctot = 128;
  __shared__ __align__(16) unsigned short Abuf[128*K];
  __shared__ float abbs[2*K];
  __shared__ float redS[2][128], redQ[2][128];
  int tid = threadIdx.x;
  int r0 = blockIdx.x*128;
  for (int e=tid; e<2*K; e+=256) abbs[e] = abbIn[e];
  __syncthreads();
  constexpr int CPR = K/8;
  for (int e=tid; e<128*CPR; e+=256){
    int row = e/CPR; int kc = (e - row*CPR)*8;
    short8 rawv = *(const short8*)(Xin + (size_t)(r0+row)*K + kc);
    short8 st;
    #pragma unroll
    for (int j=0;j<8;j++){
      float t = fmaxf(abbs[kc+j]*bf2f((unsigned short)rawv[j]) + abbs[K+kc+j], 0.f);
      st[j] = (short)f2bf(t);
    }
    unsigned byte = ((unsigned)(row*K + kc))*2u; byte ^= ((unsigned)(row&7))<<4;
    *(short8*)((char*)Abuf + byte) = st;
  }
  __syncthreads();

  int lane = tid&63, wid = tid>>6;
  int wr = wid>>1, wc = wid&1;
  int l15 = lane&15, lhi = lane>>4;
  f32x4 acc[4][4] = {};
  #pragma unroll
  for (int ks=0; ks<K/32; ks++){
    short8 af[4], bfr[4];
    int kb = ks*32 + lhi*8;
    #pragma unroll
    for (int f=0; f<4; f++){
      int arr = wr*64 + f*16 + l15;
      unsigned ab = ((unsigned)(arr*K + kb))*2u ^ (((unsigned)(arr&7))<<4);
      af[f] = *(const short8*)((const char*)Abuf + ab);
      int bc = wc*64 + f*16 + l15;
      bfr[f] = *(const short8*)&Wb[(size_t)bc*K + kb];
    }
    #pragma unroll
    for (int fi=0; fi<4; fi++)
      #pragma unroll
      for (int fj=0; fj<4; fj++)
        acc[fi][fj] = __builtin_amdgcn_mfma_f32_16x16x32_bf16(af[fi], bfr[fj], acc[fi][fj], 0, 0, 0);
  }

  #pragma unroll
  for (int fj=0; fj<4; fj++){
    int cg = wc*64 + fj*16 + l15;
    float s=0.f, q=0.f;
    #pragma unroll
    for (int fi=0; fi<4; fi++){
      #pragma unroll
      for (int qi=0; qi<4; qi++){
        float zv = acc[fi][fj][qi];
        int rg = r0 + wr*64 + fi*16 + lhi*4 + qi;
        Zout[(size_t)rg*Ctot + cg] = f2bf(zv);
        s += zv; q = fmaf(zv,zv,q);
      }
    }
    s += __shfl_xor(s,16); s += __shfl_xor(s,32);
    q += __shfl_xor(q,16); q += __shfl_xor(q,32);
    if (lhi == 0){ redS[wr][cg]=s; redQ[wr][cg]=q; }
  }
  __syncthreads();
  if (tid < 128){
    float s = redS[0][tid]+redS[1][tid];
    float q = redQ[0][tid]+redQ[1][tid];
    size_t ci = (size_t)blockIdx.x*Ctot + tid;
    ps[ci] = s;
    ps[(size_t)NB*Ctot + ci] = q;
  }
}

// ---------------- conv3 MFMA: A in LDS once, B direct from L2, 2 col-halves ----------------
__launch_bounds__(256,3)
__global__ void k_conv3mf(const unsigned short* __restrict__ Xin, const float* __restrict__ abbIn,
                          const unsigned short* __restrict__ Wb,
                          float* __restrict__ ps, int NB,
                          float* __restrict__ pm, float* __restrict__ pn){
  constexpr int K = 128, Ctot = 256;
  __shared__ __align__(16) unsigned short Abuf[128*K];
  __shared__ float abbs[2*K];
  __shared__ float redS[2][128], redQ[2][128];
  __shared__ float mxS[2][2][128], mnS[2][2][128];
  int tid = threadIdx.x;
  int r0 = blockIdx.x*128;
  for (int e=tid; e<2*K; e+=256) abbs[e] = abbIn[e];
  __syncthreads();
  constexpr int CPR = K/8;
  for (int e=tid; e<128*CPR; e+=256){
    int row = e/CPR; int kc = (e - row*CPR)*8;
    short8 rawv = *(const short8*)(Xin + (size_t)(r0+row)*K + kc);
    short8 st;
    #pragma unroll
    for (int j=0;j<8;j++){
      float t = fmaxf(abbs[kc+j]*bf2f((unsigned short)rawv[j]) + abbs[K+kc+j], 0.f);
      st[j] = (short)f2bf(t);
    }
    unsigned byte = ((unsigned)(row*K + kc))*2u; byte ^= ((unsigned)(row&7))<<4;
    *(short8*)((char*)Abuf + byte) = st;
  }
  __syncthreads();

  int lane = tid&63, wid = tid>>6;
  int wr = wid>>1, wc = wid&1;
  int l15 = lane&15, lhi = lane>>4;
  int m0 = r0/500;
  int mhi = (m0+1)*500;
  bool onem = (r0+127) < mhi;

  for (int half=0; half<2; half++){
    int c0 = half*128;
    if (half) __syncthreads();   // redS/mxS reuse

    f32x4 acc[4][4] = {};
    #pragma unroll
    for (int ks=0; ks<K/32; ks++){
      short8 af[4], bfr[4];
      int kb = ks*32 + lhi*8;
      #pragma unroll
      for (int f=0; f<4; f++){
        int arr = wr*64 + f*16 + l15;
        unsigned ab = ((unsigned)(arr*K + kb))*2u ^ (((unsigned)(arr&7))<<4);
        af[f] = *(const short8*)((const char*)Abuf + ab);
        int bc = c0 + wc*64 + f*16 + l15;
        bfr[f] = *(const short8*)&Wb[(size_t)bc*K + kb];
      }
      #pragma unroll
      for (int fi=0; fi<4; fi++)
        #pragma unroll
        for (int fj=0; fj<4; fj++)
          acc[fi][fj] = __builtin_amdgcn_mfma_f32_16x16x32_bf16(af[fi], bfr[fj], acc[fi][fj], 0, 0, 0);
    }

    if (onem){
      #pragma unroll
      for (int fj=0; fj<4; fj++){
        float s=0.f, q=0.f, mx0=-INFINITY, mn0=INFINITY;
        #pragma unroll
        for (int fi=0; fi<4; fi++){
          #pragma unroll
          for (int qi=0; qi<4; qi++){
            float zv = acc[fi][fj][qi];
            s += zv; q = fmaf(zv,zv,q);
            mx0 = fmaxf(mx0,zv); mn0 = fminf(mn0,zv);
          }
        }
        s += __shfl_xor(s,16); s += __shfl_xor(s,32);
        q += __shfl_xor(q,16); q += __shfl_xor(q,32);
        mx0 = fmaxf(mx0, __shfl_xor(mx0,16)); mx0 = fmaxf(mx0, __shfl_xor(mx0,32));
        mn0 = fminf(mn0, __shfl_xor(mn0,16)); mn0 = fminf(mn0, __shfl_xor(mn0,32));
        if (lhi == 0){
          int ch = wc*64 + fj*16 + l15;
          redS[wr][ch]=s; redQ[wr][ch]=q;
          mxS[wr][0][ch]=mx0; mxS[wr][1][ch]=-INFINITY;
          mnS[wr][0][ch]=mn0; mnS[wr][1][ch]=INFINITY;
        }
      }
    } else {
      #pragma unroll
      for (int fj=0; fj<4; fj++){
        float s=0.f, q=0.f;
        float mx0=-INFINITY,mx1=-INFINITY,mn0=INFINITY,mn1=INFINITY;
        #pragma unroll
        for (int fi=0; fi<4; fi++){
          #pragma unroll
          for (int qi=0; qi<4; qi++){
            float zv = acc[fi][fj][qi];
            int rg = r0 + wr*64 + fi*16 + lhi*4 + qi;
            s += zv; q = fmaf(zv,zv,q);
            if (rg >= mhi){ mx1=fmaxf(mx1,zv); mn1=fminf(mn1,zv); }
            else          { mx0=fmaxf(mx0,zv); mn0=fminf(mn0,zv); }
          }
        }
        s += __shfl_xor(s,16); s += __shfl_xor(s,32);
        q += __shfl_xor(q,16); q += __shfl_xor(q,32);
        mx0 = fmaxf(mx0, __shfl_xor(mx0,16)); mx0 = fmaxf(mx0, __shfl_xor(mx0,32));
        mx1 = fmaxf(mx1, __shfl_xor(mx1,16)); mx1 = fmaxf(mx1, __shfl_xor(mx1,32));
        mn0 = fminf(mn0, __shfl_xor(mn0,16)); mn0 = fminf(mn0, __shfl_xor(mn0,32));
        mn1 = fminf(mn1, __shfl_xor(mn1,16)); mn1 = fminf(mn1, __shfl_xor(mn1,32));
        if (lhi == 0){
          int ch = wc*64 + fj*16 + l15;
          redS[wr][ch]=s; redQ[wr][ch]=q;
          mxS[wr][0][ch]=mx0; mxS[wr][1][ch]=mx1;
          mnS[wr][0][ch]=mn0; mnS[wr][1][ch]=mn1;
        }
      }
    }
    __syncthreads();
    if (tid < 128){
      float s = redS[0][tid]+redS[1][tid];
      float q = redQ[0][tid]+redQ[1][tid];
      size_t ci = (size_t)blockIdx.x*Ctot + c0 + tid;
      ps[ci] = s;
      ps[(size_t)NB*Ctot + ci] = q;
      #pragma unroll
      for (int g=0; g<2; g++){
        pm[((size_t)blockIdx.x*2+g)*Ctot + c0 + tid] = fmaxf(mxS[0][g][tid], mxS[1][g][tid]);
        pn[((size_t)blockIdx.x*2+g)*Ctot + c0 + tid] = fminf(mnS[0][g][tid], mnS[1][g][tid]);
      }
    }
  }
}

// ---------------- fused pool + FC1: one block per output row ----------------
__launch_bounds__(256)
__global__ void k_poolfc1(const float* __restrict__ pm, const float* __restrict__ pn,
                          const float* __restrict__ abb3, const float* __restrict__ FC1W,
                          float* __restrict__ Z4){
  __shared__ float of[256];
  int r = blockIdx.x;
  int tid = threadIdx.x;
  {
    int c = tid;
    int bxlo = (500*r)/128;
    int bxhi = (500*r+499)/128;
    float mx=-INFINITY, mn=INFINITY;
    for (int bx=bxlo; bx<=bxhi; bx++){
      int mb = (bx*128)/500;
      int gg = r - mb;
      if (gg==0 || gg==1){
        mx = fmaxf(mx, pm[((size_t)bx*2+gg)*256 + c]);
        mn = fminf(mn, pn[((size_t)bx*2+gg)*256 + c]);
      }
    }
    float a = abb3[c], bb = abb3[256+c];
    float zv = (a >= 0.f) ? mx : mn;
    of[c] = fmaxf(a*zv + bb, 0.f);
  }
  __syncthreads();
  if (tid < 128){
    float acc = 0.f;
    const float* wr = &FC1W[(size_t)tid*256];
    #pragma unroll 4
    for (int k=0;k<256;k++) acc = fmaf(of[k], wr[k], acc);
    Z4[(size_t)r*128 + tid] = acc;
  }
}

// ---------------- FC2: wave per output ----------------
__launch_bounds__(256)
__global__ void k_fc(const float* __restrict__ A, const float* __restrict__ W,
                     const float* __restrict__ abb, float* __restrict__ C,
                     int Ncols, int K){
  int gw = blockIdx.x*4 + (threadIdx.x>>6);
  int lane = threadIdx.x & 63;
  int r = gw / Ncols, c = gw - r*Ncols;
  float s = 0.f;
  for (int k=lane; k<K; k+=64){
    float v = A[(size_t)r*K + k];
    if (abb) v = fmaxf(abb[k]*v + abb[K+k], 0.f);
    s = fmaf(v, W[(size_t)c*K + k], s);
  }
  #pragma unroll
  for (int off=1; off<64; off<<=1) s += __shfl_xor(s,off);
  if (lane==0) C[(size_t)r*Ncols + c] = s;
}

// one LSTM step; 256 blocks (2 u-columns each) x 512 thr; wave = (ul,gate), lane = (seg,b); whh bf16
__launch_bounds__(512)
__global__ void k_lstm_step(const float* __restrict__ hprev, float* __restrict__ hnext,
                            const float* __restrict__ cin, float* __restrict__ cout,
                            const float* __restrict__ embw, const int* __restrict__ aa,
                            const unsigned short* __restrict__ whhb, float* __restrict__ lout,
                            float* __restrict__ outhc, int t){
  __shared__ float h_s[16][516];
  __shared__ float g_s[8][16];
  int tid = threadIdx.x;
  int u0 = blockIdx.x*2;
  for (int e=tid; e<2048; e+=512){
    int idx = e*4;
    *(float4*)&h_s[idx>>9][idx&511] = *(const float4*)&hprev[idx];
  }
  __syncthreads();
  int w = tid>>6, lane = tid&63;
  int ul = w>>2, gate = w&3;
  int seg = lane>>4, b = lane&15;
  int j = gate*512 + u0 + ul;
  const short8* wrow = (const short8*)&whhb[(size_t)j*512 + seg*128];
  const float* hrow = &h_s[b][seg*128];
  float a0=0.f, a1=0.f;
  #pragma unroll
  for (int k=0;k<16;k++){
    short8 wv = wrow[k];
    const float4* hp4 = (const float4*)(hrow + k*8);
    float4 h0 = hp4[0], h1 = hp4[1];
    a0 = fmaf(h0.x, bf2f((unsigned short)wv[0]), a0);
    a1 = fmaf(h0.y, bf2f((unsigned short)wv[1]), a1);
    a0 = fmaf(h0.z, bf2f((unsigned short)wv[2]), a0);
    a1 = fmaf(h0.w, bf2f((unsigned short)wv[3]), a1);
    a0 = fmaf(h1.x, bf2f((unsigned short)wv[4]), a0);
    a1 = fmaf(h1.y, bf2f((unsigned short)wv[5]), a1);
    a0 = fmaf(h1.z, bf2f((unsigned short)wv[6]), a0);
    a1 = fmaf(h1.w, bf2f((unsigned short)wv[7]), a1);
  }
  float s = a0 + a1;
  s += __shfl_xor(s,16);
  s += __shfl_xor(s,32);
  if (lane < 16){
    int v = aa[lane*Tt + t];
    g_s[w][lane] = s + embw[(size_t)v*2048 + j];
  }
  __syncthreads();
  if (tid < 32){
    int ul2 = tid>>4, b2 = tid&15;
    float iv = g_s[ul2*4+0][b2], fv = g_s[ul2*4+1][b2];
    float gv = g_s[ul2*4+2][b2], ov = g_s[ul2*4+3][b2];
    int ci = b2*512 + u0 + ul2;
    float cn = sigf(fv)*cin[ci] + sigf(iv)*tanhf(gv);
    float hn = sigf(ov)*tanhf(cn);
    cout[ci]=cn; hnext[ci]=hn;
    lout[(size_t)(b2*Tt + t)*Hh + u0 + ul2] = hn;
    if (outhc){ outhc[Mm*Vv + ci] = hn; outhc[Mm*Vv + Bb*Hh + ci] = cn; }
  }
}

// logits: one block per output row; 8-lane dot groups over 26 outputs
__launch_bounds__(256)
__global__ void k_logits(const float* __restrict__ Z5, const float* __restrict__ abb5,
                         const float* __restrict__ lout, const float* __restrict__ outw,
                         const float* __restrict__ outb, float* __restrict__ out){
  __shared__ float of[576];
  int r = blockIdx.x;
  int tid = threadIdx.x;
  if (tid < 64) of[tid] = fmaxf(abb5[tid]*Z5[(size_t)r*64+tid] + abb5[64+tid], 0.f);
  for (int e=tid; e<512; e+=256) of[64+e] = fmaxf(lout[(size_t)r*512+e], 0.f);
  __syncthreads();
  int o = tid>>3, k0 = tid&7;
  if (o < Vv){
    float acc = 0.f;
    for (int k=k0; k<576; k+=8) acc = fmaf(of[k], outw[o*576+k], acc);
    acc += __shfl_xor(acc,1); acc += __shfl_xor(acc,2); acc += __shfl_xor(acc,4);
    if (k0==0) out[r*Vv + o] = acc + outb[o];
  }
}

extern "C" void kernel_launch(void* const* d_in, const int* in_sizes, int n_in,
                              void* d_out, int out_size, void* d_ws, size_t ws_size,
                              hipStream_t stream){
  (void)in_sizes; (void)n_in; (void)out_size; (void)ws_size;
  const float* L   = (const float*)d_in[0];
  const float* PL  = (const float*)d_in[1];
  const float* PI  = (const float*)d_in[2];
  const int*   AA  = (const int*)d_in[3];
  const float* H0  = (const float*)d_in[4];
  const float* C0  = (const float*)d_in[5];
  const float* DSF = (const float*)d_in[6];
  const float* W1  = (const float*)d_in[7];
  const float* W2  = (const float*)d_in[9];
  const float* W3  = (const float*)d_in[11];
  const float* FC1W= (const float*)d_in[13];
  const float* FC2W= (const float*)d_in[15];
  const float* G0=(const float*)d_in[17]; const float* Bt0=(const float*)d_in[18];
  const float* G1=(const float*)d_in[19]; const float* Bt1=(const float*)d_in[20];
  const float* G2=(const float*)d_in[21]; const float* Bt2=(const float*)d_in[22];
  const float* G3=(const float*)d_in[23]; const float* Bt3=(const float*)d_in[24];
  const float* G4=(const float*)d_in[25]; const float* Bt4=(const float*)d_in[26];
  const float* G5=(const float*)d_in[27]; const float* Bt5=(const float*)d_in[28];
  const float* EMB=(const float*)d_in[29];
  const float* WIH=(const float*)d_in[30];
  const float* WHH=(const float*)d_in[31];
  const float* BIH=(const float*)d_in[32];
  const float* BHH=(const float*)d_in[33];
  const float* OUTW=(const float*)d_in[34];
  const float* OUTB=(const float*)d_in[35];
  float* out = (float*)d_out;
  float* ws  = (float*)d_ws;

  size_t o = 0;
  unsigned short* Z1B = (unsigned short*)(ws+o); o += (size_t)Rr*32;   // Rr*64 bf16
  unsigned short* Z2B = (unsigned short*)(ws+o); o += (size_t)Rr*64;   // Rr*128 bf16
  float* PS0   = ws+o; o += 2*4096*CIN + 16;
  float* PS1   = ws+o; o += 2*NB1*64 + 16;
  float* PS2   = ws+o; o += 2*NB23*128 + 16;
  float* PS3   = ws+o; o += 2*NB23*256 + 16;
  float* PM3   = ws+o; o += NB23*2*256 + 16;
  float* PN3   = ws+o; o += NB23*2*256 + 16;
  float* ABB1  = ws+o; o += 128;
  float* ABB2  = ws+o; o += 256;
  float* ABB3  = ws+o; o += 512;
  float* ABB4  = ws+o; o += 256;
  float* ABB5  = ws+o; o += 128;
  unsigned short* W1B = (unsigned short*)(ws+o); o += 64*K1P/2 + 16;
  unsigned short* W2B = (unsigned short*)(ws+o); o += 4096 + 16;
  unsigned short* W3B = (unsigned short*)(ws+o); o += 16384 + 16;
  unsigned short* WHHB = (unsigned short*)(ws+o); o += 524288 + 16;   // 1M bf16
  float* Z4    = ws+o; o += 65536;
  float* Z5    = ws+o; o += 32768;
  float* EMBW  = ws+o; o += 53248;
  float* HB0   = ws+o; o += 8192;
  float* HB1   = ws+o; o += 8192;
  float* CB    = ws+o; o += 8192;
  float* LOUT  = ws+o; o += 262144;

  // front: converts (incl WHH->bf16) | embw dots | bn0 partial stats — single launch
  k_front<<<21676,256,0,stream>>>(W2,W3,WHH,EMB,WIH,BIH,BHH,L,PL,PI,DSF,
                                  W2B,W3B,W1B,WHHB,EMBW,PS0);

  // point cloud branch
  k_reduce0<<<CIN,256,0,stream>>>(PS0,G0,W1,W1B);
  k_conv1mf<<<NB1,256,0,stream>>>(L,PL,PI,DSF,W1B,Z1B,PS1);
  k_reduce_ps<<<64,256,0,stream>>>(PS1, NB1, 64, 1.0f/(float)Rr, G1, Bt1, ABB1);
  k_convmf<<<NB23,256,0,stream>>>(Z1B,ABB1,W2B,Z2B,PS2,NB23);
  k_reduce_ps<<<128,256,0,stream>>>(PS2, NB23, 128, 1.0f/(float)Rr, G2, Bt2, ABB2);
  k_conv3mf<<<NB23,256,0,stream>>>(Z2B,ABB2,W3B,PS3,NB23,PM3,PN3);
  k_reduce_ps<<<256,256,0,stream>>>(PS3, NB23, 256, 1.0f/(float)Rr, G3, Bt3, ABB3);
  k_poolfc1<<<512,256,0,stream>>>(PM3,PN3,ABB3,FC1W,Z4);
  k_colstats_par<<<128,256,0,stream>>>(Z4,512,128,G4,Bt4,ABB4);
  k_fc<<<8192,256,0,stream>>>(Z4,FC2W,ABB4,Z5,64,128);
  k_colstats_par<<<64,256,0,stream>>>(Z5,512,64,G5,Bt5,ABB5);

  // LSTM branch — 32 step launches (init/out fused into steps 0/31), whh in bf16
  for (int t=0;t<32;t++){
    const float* hp = (t==0) ? H0 : ((t&1)?HB1:HB0);
    float* hn = (t&1)?HB0:HB1;
    const float* ci = (t==0) ? C0 : CB;
    float* outhc = (t==31) ? out : nullptr;
    k_lstm_step<<<256,512,0,stream>>>(hp,hn,ci,CB,EMBW,AA,WHHB,LOUT,outhc,t);
  }

  // output head
  k_logits<<<512,256,0,stream>>>(Z5,ABB5,LOUT,OUTW,OUTB,out);
}